// Round 4
// baseline (1970.802 us; speedup 1.0000x reference)
//
#include <hip/hip_runtime.h>
#include <math.h>

#define EPS_C 0.001f
#define BATCH 16384
#define FLAG_SIG 0x600D0000

// ---------------- H = X^T X + eps*I  (1152x1152), symmetric: compute bi<=bj, mirror ----------------
__global__ __launch_bounds__(256) void k_xtx(const float* __restrict__ X, float* __restrict__ H) {
  __shared__ float smem[64 * 65];
  const int bi64 = blockIdx.x, bj64 = blockIdx.y;
  if (bi64 > bj64) return;
  float (*sA)[65] = (float(*)[65])smem;
  float (*sB)[65] = (float(*)[65])(smem + 32 * 65);
  const int t = threadIdx.x;
  const int bi = bi64 * 64, bj = bj64 * 64;
  const int tj = t & 15, ti = t >> 4;
  float acc[4][4] = {};
  for (int k0 = 0; k0 < 1152; k0 += 32) {
    #pragma unroll
    for (int l = 0; l < 2; ++l) {
      int idx = t + l * 256;
      int kk = idx >> 4, c4 = (idx & 15) << 2;
      float4 va = *(const float4*)&X[(k0 + kk) * 1152 + bi + c4];
      sA[kk][c4 + 0] = va.x; sA[kk][c4 + 1] = va.y; sA[kk][c4 + 2] = va.z; sA[kk][c4 + 3] = va.w;
      float4 vb = *(const float4*)&X[(k0 + kk) * 1152 + bj + c4];
      sB[kk][c4 + 0] = vb.x; sB[kk][c4 + 1] = vb.y; sB[kk][c4 + 2] = vb.z; sB[kk][c4 + 3] = vb.w;
    }
    __syncthreads();
    #pragma unroll
    for (int kk = 0; kk < 32; ++kk) {
      float am[4], bn[4];
      #pragma unroll
      for (int q = 0; q < 4; ++q) am[q] = sA[kk][ti * 4 + q];
      #pragma unroll
      for (int q = 0; q < 4; ++q) bn[q] = sB[kk][tj * 4 + q];
      #pragma unroll
      for (int r = 0; r < 4; ++r)
        #pragma unroll
        for (int c = 0; c < 4; ++c)
          acc[r][c] = fmaf(am[r], bn[c], acc[r][c]);
    }
    __syncthreads();
  }
  #pragma unroll
  for (int r = 0; r < 4; ++r) {
    int gi = bi + ti * 4 + r;
    float vv[4];
    #pragma unroll
    for (int c = 0; c < 4; ++c) {
      vv[c] = acc[r][c];
      if (gi == bj + tj * 4 + c) vv[c] += EPS_C;
    }
    float4 o = make_float4(vv[0], vv[1], vv[2], vv[3]);
    *(float4*)&H[gi * 1152 + bj + tj * 4] = o;
  }
  if (bi64 < bj64) {
    // transpose through LDS (sA/sB dead after final barrier), coalesced mirror write
    float (*tr)[65] = (float(*)[65])smem;
    #pragma unroll
    for (int r = 0; r < 4; ++r)
      #pragma unroll
      for (int c = 0; c < 4; ++c)
        tr[tj * 4 + c][ti * 4 + r] = acc[r][c];
    __syncthreads();
    #pragma unroll
    for (int l = 0; l < 4; ++l) {
      int e = t + l * 256;
      int row = e >> 4, c4 = (e & 15) << 2;
      float4 o = make_float4(tr[row][c4], tr[row][c4 + 1], tr[row][c4 + 2], tr[row][c4 + 3]);
      *(float4*)&H[(bj + row) * 1152 + bi + c4] = o;
    }
  }
}

// ---------------- assemble M=[E^T | C2^T], D11, Lam, xc, Fx; zero sync flags ----------------
__global__ __launch_bounds__(256) void k_assemble(const float* __restrict__ H, const float* __restrict__ Y,
                           const float* __restrict__ C2, const float* __restrict__ x0,
                           float* __restrict__ M, float* __restrict__ D11,
                           float* __restrict__ Lam, float* __restrict__ xc, float* __restrict__ Fx,
                           int* __restrict__ flags) {
  const int b = blockIdx.x;
  const int t = threadIdx.x;
  if (b < 256) {
    __shared__ float tA[32][33], tB[32][33], tC[32][33];
    const int R0 = (b & 15) * 32, C0 = (b >> 4) * 32;
    const int c = t & 31, rr = t >> 5;
    #pragma unroll
    for (int p = 0; p < 4; ++p) {
      int row = rr + p * 8; // local cc index
      tA[row][c] = H[(C0 + row) * 1152 + R0 + c];
      tB[row][c] = H[(640 + C0 + row) * 1152 + 640 + R0 + c];
      tC[row][c] = Y[(C0 + row) * 512 + R0 + c];
    }
    __syncthreads();
    #pragma unroll
    for (int p = 0; p < 4; ++p) {
      int r = rr + p * 8; // local row
      float val = 0.5f * (tA[c][r] + tB[c][r] + tC[c][r] - Y[(R0 + r) * 512 + C0 + c]);
      M[(R0 + r) * 640 + C0 + c] = val;
    }
  } else if (b < 320) {
    int e0 = (b - 256) * 1024;
    #pragma unroll
    for (int l = 0; l < 4; ++l) {
      int e = e0 + l * 256 + t;
      int r = e >> 7, o = e & 127;
      M[r * 640 + 512 + o] = C2[o * 512 + r];
    }
  } else if (b < 384) {
    int e = (b - 320) * 256 + t;
    int i = e >> 7, j = e & 127;
    D11[e] = (j < i) ? -H[(512 + i) * 1152 + 512 + j] : 0.0f;
  } else if (b == 384) {
    if (t < 128) Lam[t] = 0.5f * H[(512 + t) * 1152 + 512 + t];
  } else if (b == 385) {
    if (t < 128) {
      float s = 0.f;
      for (int a = 0; a < 512; ++a) s = fmaf(H[(512 + t) * 1152 + a], x0[a], s);
      xc[t] = -s;
    }
  } else if (b < 388) {
    int r = (b - 386) * 256 + t;
    float s = 0.f;
    for (int a = 0; a < 512; ++a) s = fmaf(H[(640 + r) * 1152 + a], x0[a], s);
    Fx[r] = s;
  } else {
    if (t < 32) flags[t] = 0;
  }
}

// ---------------- fused LU step: panel blocks (redundant in-register diag factor, no waits)
//                  release-count into pcnt; trailing blocks relaxed-poll pcnt==npan then update.
//                  Factored diag goes to Dfac (NOT in-place) so sibling reads of M's diag are race-free. ----------------
__global__ __launch_bounds__(256) void k_lu_step(float* __restrict__ M, float* __restrict__ Dfac,
                                                 int kb, int* __restrict__ pcnt) {
  __shared__ float smem[64 * 65 + 64];
  const int t = threadIdx.x;
  const int b = blockIdx.x;
  const int npan = 16 - 2 * kb;
  if (b < npan) {
    float* sD = smem;
    float* sRD = smem + 64 * 65;
    const int nU = 9 - kb;
    const int pb = b;
    if (t < 64) {  // single wave does everything; LDS deps are in-wave (program-order safe)
      float v[64];
      int c = 0, rr = 0;
      if (pb < nU) {
        c = 64 * (kb + 1) + pb * 64 + t;
        #pragma unroll
        for (int i = 0; i < 64; ++i) v[i] = M[(kb * 64 + i) * 640 + c];
      } else {
        rr = 64 * (kb + 1) + (pb - nU) * 64 + t;
        #pragma unroll
        for (int i = 0; i < 16; ++i) *(float4*)&v[i * 4] = *(const float4*)&M[rr * 640 + kb * 64 + i * 4];
      }
      // redundant in-register LU factor of diag (reads ORIGINAL M diag; pb0 writes factored copy to Dfac)
      {
        const float* blk = M + kb * 64 * 640 + kb * 64;
        float col[64];
        #pragma unroll
        for (int r = 0; r < 64; ++r) col[r] = blk[r * 640 + t];
        float invp = 1.0f;
        #pragma unroll
        for (int k = 0; k < 64; ++k) {
          float piv = __shfl(col[k], k);
          float inv = 1.0f / piv;
          if (t == k) invp = inv;
          float m = col[k] * inv;
          bool act = t > k;
          #pragma unroll
          for (int r = k + 1; r < 64; ++r) {
            float ckr = __shfl(col[r], k);
            if (act) col[r] -= ckr * m;
          }
        }
        #pragma unroll
        for (int r = 0; r < 64; ++r) {
          if (r > t) col[r] *= invp;
          sD[r * 65 + t] = col[r];
          if (pb == 0) Dfac[kb * 4096 + r * 64 + t] = col[r];
        }
        sRD[t] = invp;  // == 1/sD[t*65+t] bitwise
      }
      if (pb < nU) {
        #pragma unroll
        for (int i = 1; i < 64; ++i) {
          float a0 = v[i], a1 = 0.f;
          #pragma unroll
          for (int j = 0; j < i; j += 2) {
            a0 = fmaf(-sD[i * 65 + j], v[j], a0);
            if (j + 1 < i) a1 = fmaf(-sD[i * 65 + j + 1], v[j + 1], a1);
          }
          v[i] = a0 + a1;
        }
        #pragma unroll
        for (int i = 0; i < 64; ++i) M[(kb * 64 + i) * 640 + c] = v[i];
      } else {
        #pragma unroll
        for (int j = 0; j < 64; ++j) {
          float a0 = v[j], a1 = 0.f;
          #pragma unroll
          for (int i = 0; i < j; i += 2) {
            a0 = fmaf(-v[i], sD[i * 65 + j], a0);
            if (i + 1 < j) a1 = fmaf(-v[i + 1], sD[(i + 1) * 65 + j], a1);
          }
          v[j] = (a0 + a1) * sRD[j];
        }
        #pragma unroll
        for (int i = 0; i < 16; ++i) *(float4*)&M[rr * 640 + kb * 64 + i * 4] = *(float4*)&v[i * 4];
      }
    }
    __syncthreads();   // drains wave-0's global stores before the signal
    if (t == 0) {
      __threadfence();
      __hip_atomic_fetch_add(pcnt, 1, __ATOMIC_RELEASE, __HIP_MEMORY_SCOPE_AGENT);
    }
  } else {
    // ---- trailing: A22 -= L21 * U12 ----
    float (*sL)[65] = (float(*)[65])smem;
    float (*sU)[65] = (float(*)[65])((float*)smem + 32 * 65);
    const int e0 = b - npan;
    const int ncol = 9 - kb;
    const int jB = e0 % ncol, iB = e0 / ncol;
    const int base = 64 * (kb + 1);
    const int r0 = base + iB * 64, c0 = base + jB * 64;
    const int tj = t & 15, ti = t >> 4;
    if (t == 0) {
      while (__hip_atomic_load(pcnt, __ATOMIC_RELAXED, __HIP_MEMORY_SCOPE_AGENT) != npan)
        __builtin_amdgcn_s_sleep(1);
      (void)__hip_atomic_load(pcnt, __ATOMIC_ACQUIRE, __HIP_MEMORY_SCOPE_AGENT);
    }
    __syncthreads();
    float acc[4][4] = {};
    for (int k0 = 0; k0 < 64; k0 += 32) {
      #pragma unroll
      for (int l = 0; l < 2; ++l) {
        int idx = t + l * 256;
        int row = idx >> 3, k4 = (idx & 7) << 2;
        float4 v = *(const float4*)&M[(r0 + row) * 640 + kb * 64 + k0 + k4];
        sL[k4 + 0][row] = v.x; sL[k4 + 1][row] = v.y; sL[k4 + 2][row] = v.z; sL[k4 + 3][row] = v.w;
        int kk = idx >> 4, c4 = (idx & 15) << 2;
        float4 u4 = *(const float4*)&M[(kb * 64 + k0 + kk) * 640 + c0 + c4];
        sU[kk][c4 + 0] = u4.x; sU[kk][c4 + 1] = u4.y; sU[kk][c4 + 2] = u4.z; sU[kk][c4 + 3] = u4.w;
      }
      __syncthreads();
      #pragma unroll
      for (int kk = 0; kk < 32; ++kk) {
        float am[4], bn[4];
        #pragma unroll
        for (int q = 0; q < 4; ++q) am[q] = sL[kk][ti * 4 + q];
        #pragma unroll
        for (int q = 0; q < 4; ++q) bn[q] = sU[kk][tj * 4 + q];
        #pragma unroll
        for (int r = 0; r < 4; ++r)
          #pragma unroll
          for (int c = 0; c < 4; ++c)
            acc[r][c] = fmaf(am[r], bn[c], acc[r][c]);
      }
      __syncthreads();
    }
    #pragma unroll
    for (int r = 0; r < 4; ++r) {
      float4 old = *(float4*)&M[(r0 + ti * 4 + r) * 640 + c0 + tj * 4];
      old.x -= acc[r][0]; old.y -= acc[r][1]; old.z -= acc[r][2]; old.w -= acc[r][3];
      *(float4*)&M[(r0 + ti * 4 + r) * 640 + c0 + tj * 4] = old;
    }
  }
}

// ---------------- backward solve U * Gt = Z : 8 blocks, relaxed-poll chained; solve IN LDS (no v[64] spill) ----------------
__global__ __launch_bounds__(512) void k_bs(float* __restrict__ M, const float* __restrict__ Dfac,
                                            float* __restrict__ Gt, int* __restrict__ flags) {
  __shared__ float sU[64 * 65];
  __shared__ float sX[64 * 128];
  __shared__ float srs[64];
  const int kb = blockIdx.x;       // row block owned
  const int t = threadIdx.x;
  const int o = t & 127, q = t >> 7;
  float z[16];
  #pragma unroll
  for (int r = 0; r < 16; ++r) z[r] = M[(kb * 64 + q * 16 + r) * 640 + 512 + o];

  for (int j = 7; j > kb; --j) {
    // prestage U_{kb,j} (ready at launch) -- overlaps the flag wait
    #pragma unroll
    for (int l = 0; l < 8; ++l) {
      int e = t + l * 512;
      int r = e >> 6, k = e & 63;
      sU[r * 65 + k] = M[(kb * 64 + r) * 640 + j * 64 + k];
    }
    if (t == 0) {
      while (__hip_atomic_load(&flags[j], __ATOMIC_RELAXED, __HIP_MEMORY_SCOPE_AGENT) != (FLAG_SIG + j))
        __builtin_amdgcn_s_sleep(1);
      (void)__hip_atomic_load(&flags[j], __ATOMIC_ACQUIRE, __HIP_MEMORY_SCOPE_AGENT);
    }
    __syncthreads();
    #pragma unroll
    for (int l = 0; l < 16; ++l) {
      int e = t + l * 512;
      int k = e >> 7, o2 = e & 127;
      sX[k * 128 + o2] = Gt[(j * 64 + k) * 128 + o2];
    }
    __syncthreads();
    for (int k = 0; k < 64; ++k) {
      float xk = sX[k * 128 + o];
      #pragma unroll
      for (int r = 0; r < 16; ++r)
        z[r] = fmaf(-sU[(q * 16 + r) * 65 + k], xk, z[r]);
    }
    __syncthreads();
  }

  // dump z to LDS (reuse sX as Z), stage factored diag from Dfac, solve in LDS
  #pragma unroll
  for (int r = 0; r < 16; ++r) sX[(q * 16 + r) * 128 + o] = z[r];
  #pragma unroll
  for (int l = 0; l < 8; ++l) {
    int e = t + l * 512;
    int r = e >> 6, k = e & 63;
    sU[r * 65 + k] = Dfac[kb * 4096 + r * 64 + k];
  }
  __syncthreads();
  if (t < 64) srs[t] = 1.0f / sU[t * 65 + t];
  __syncthreads();
  if (t < 128) {
    #pragma unroll
    for (int i = 63; i >= 0; --i) {
      float a0 = sX[i * 128 + t], a1 = 0.f;
      #pragma unroll
      for (int jj = i + 1; jj < 64; jj += 2) {
        a0 = fmaf(-sU[i * 65 + jj], sX[jj * 128 + t], a0);
        if (jj + 1 < 64) a1 = fmaf(-sU[i * 65 + jj + 1], sX[(jj + 1) * 128 + t], a1);
      }
      sX[i * 128 + t] = (a0 + a1) * srs[i];
    }
    #pragma unroll
    for (int i = 0; i < 64; ++i) Gt[(kb * 64 + i) * 128 + t] = sX[i * 128 + t];
  }
  __threadfence();
  __syncthreads();
  if (t == 0)
    __hip_atomic_store(&flags[kb], FLAG_SIG + kb, __ATOMIC_RELEASE, __HIP_MEMORY_SCOPE_AGENT);
}

// ---------------- W1 = G@B1 + D21, W2 = G@B2 + D22, bias = G@Fx ----------------
__global__ void k_wass(const float* __restrict__ Gt, const float* __restrict__ H,
                       const float* __restrict__ B2, const float* __restrict__ D21,
                       const float* __restrict__ D22, const float* __restrict__ Fx,
                       float* __restrict__ W1, float* __restrict__ W2, float* __restrict__ bias) {
  int idx = blockIdx.x * 256 + threadIdx.x;
  if (idx < 16384) {
    int o = idx >> 7, j = idx & 127;
    float s = 0.f;
    for (int a = 0; a < 512; ++a) s = fmaf(Gt[a * 128 + o], H[(640 + a) * 1152 + 512 + j], s);
    W1[idx] = s + D21[idx];
  } else if (idx < 32768) {
    int q = idx - 16384;
    int o = q >> 7, j = q & 127;
    float s = 0.f;
    for (int a = 0; a < 512; ++a) s = fmaf(Gt[a * 128 + o], B2[a * 128 + j], s);
    W2[q] = s + D22[q];
  } else if (idx < 32768 + 128) {
    int o = idx - 32768;
    float s = 0.f;
    for (int a = 0; a < 512; ++a) s = fmaf(Gt[a * 128 + o], Fx[a], s);
    bias[o] = s;
  }
}

// ---------------- baseT[i][b] = xc[i] + (u @ D12^T)[b][i] ----------------
__global__ __launch_bounds__(256) void k_ud(const float* __restrict__ u, const float* __restrict__ D12,
                                            const float* __restrict__ xc, float* __restrict__ baseT) {
  __shared__ float sU[32][65];
  __shared__ float sD[32][65];
  const int t = threadIdx.x;
  const int b0 = blockIdx.x * 64, i0 = blockIdx.y * 64;
  const int tm = t & 15, tn = t >> 4;
  float acc[4][4] = {};
  for (int k0 = 0; k0 < 128; k0 += 32) {
    #pragma unroll
    for (int l = 0; l < 2; ++l) {
      int idx = t + l * 256;
      int row = idx >> 3, k4 = (idx & 7) << 2;
      float4 v = *(const float4*)&u[(b0 + row) * 128 + k0 + k4];
      sU[k4 + 0][row] = v.x; sU[k4 + 1][row] = v.y; sU[k4 + 2][row] = v.z; sU[k4 + 3][row] = v.w;
      float4 d = *(const float4*)&D12[(i0 + row) * 128 + k0 + k4];
      sD[k4 + 0][row] = d.x; sD[k4 + 1][row] = d.y; sD[k4 + 2][row] = d.z; sD[k4 + 3][row] = d.w;
    }
    __syncthreads();
    #pragma unroll
    for (int kk = 0; kk < 32; ++kk) {
      float mm[4], nn[4];
      #pragma unroll
      for (int q = 0; q < 4; ++q) mm[q] = sU[kk][tm * 4 + q];
      #pragma unroll
      for (int q = 0; q < 4; ++q) nn[q] = sD[kk][tn * 4 + q];
      #pragma unroll
      for (int c = 0; c < 4; ++c)
        #pragma unroll
        for (int r = 0; r < 4; ++r)
          acc[c][r] = fmaf(nn[c], mm[r], acc[c][r]);
    }
    __syncthreads();
  }
  #pragma unroll
  for (int c = 0; c < 4; ++c) {
    int i = i0 + tn * 4 + c;
    float xcv = xc[i];
    float4 v = make_float4(acc[c][0] + xcv, acc[c][1] + xcv, acc[c][2] + xcv, acc[c][3] + xcv);
    *(float4*)&baseT[i * BATCH + b0 + tm * 4] = v;
  }
}

// ---------------- scan: w[i] = tanh((base_i + sum_{j<i} D11[i][j] w[j]) / Lam[i]) ----------------
__global__ __launch_bounds__(64) void k_scan(const float* __restrict__ baseT, const float* __restrict__ D11g,
                                             const float* __restrict__ Lam, float* __restrict__ wT) {
  const int b = blockIdx.x * 64 + threadIdx.x;
  float w[128];
  #pragma unroll
  for (int i = 0; i < 128; ++i) {
    float acc0 = baseT[i * BATCH + b], acc1 = 0.f, acc2 = 0.f, acc3 = 0.f;
    const float* __restrict__ Drow = D11g + i * 128;
    #pragma unroll
    for (int j = 0; j + 4 <= i; j += 4) {
      acc0 = fmaf(w[j + 0], Drow[j + 0], acc0);
      acc1 = fmaf(w[j + 1], Drow[j + 1], acc1);
      acc2 = fmaf(w[j + 2], Drow[j + 2], acc2);
      acc3 = fmaf(w[j + 3], Drow[j + 3], acc3);
    }
    #pragma unroll
    for (int j = i & ~3; j < i; ++j) acc0 = fmaf(w[j], Drow[j], acc0);
    float zv = ((acc0 + acc1) + (acc2 + acc3)) / Lam[i];
    float az = fabsf(zv);
    float e = __expf(-2.0f * az);
    float th = (1.0f - e) / (1.0f + e);
    w[i] = copysignf(th, zv);
    wT[i * BATCH + b] = w[i];
  }
}

// ---------------- y = w@W1^T + u@W2^T + bias ----------------
__global__ __launch_bounds__(256) void k_y(const float* __restrict__ wT, const float* __restrict__ u,
                                           const float* __restrict__ W1, const float* __restrict__ W2,
                                           const float* __restrict__ bias, float* __restrict__ y) {
  __shared__ float sA[32][65];
  __shared__ float sW[32][65];
  const int t = threadIdx.x;
  const int b0 = blockIdx.x * 64, o0 = blockIdx.y * 64;
  const int tn = t & 15, tm = t >> 4;
  float acc[4][4] = {};
  for (int k0 = 0; k0 < 128; k0 += 32) {
    #pragma unroll
    for (int l = 0; l < 2; ++l) {
      int idx = t + l * 256;
      int kk = idx >> 4, c4 = (idx & 15) << 2;
      float4 v = *(const float4*)&wT[(k0 + kk) * BATCH + b0 + c4];
      sA[kk][c4 + 0] = v.x; sA[kk][c4 + 1] = v.y; sA[kk][c4 + 2] = v.z; sA[kk][c4 + 3] = v.w;
      int row = idx >> 3, k4 = (idx & 7) << 2;
      float4 d = *(const float4*)&W1[(o0 + row) * 128 + k0 + k4];
      sW[k4 + 0][row] = d.x; sW[k4 + 1][row] = d.y; sW[k4 + 2][row] = d.z; sW[k4 + 3][row] = d.w;
    }
    __syncthreads();
    #pragma unroll
    for (int kk = 0; kk < 32; ++kk) {
      float mm[4], nn[4];
      #pragma unroll
      for (int q = 0; q < 4; ++q) mm[q] = sA[kk][tm * 4 + q];
      #pragma unroll
      for (int q = 0; q < 4; ++q) nn[q] = sW[kk][tn * 4 + q];
      #pragma unroll
      for (int r = 0; r < 4; ++r)
        #pragma unroll
        for (int c = 0; c < 4; ++c)
          acc[r][c] = fmaf(mm[r], nn[c], acc[r][c]);
    }
    __syncthreads();
  }
  for (int k0 = 0; k0 < 128; k0 += 32) {
    #pragma unroll
    for (int l = 0; l < 2; ++l) {
      int idx = t + l * 256;
      int row = idx >> 3, k4 = (idx & 7) << 2;
      float4 v = *(const float4*)&u[(b0 + row) * 128 + k0 + k4];
      sA[k4 + 0][row] = v.x; sA[k4 + 1][row] = v.y; sA[k4 + 2][row] = v.z; sA[k4 + 3][row] = v.w;
      float4 d = *(const float4*)&W2[(o0 + row) * 128 + k0 + k4];
      sW[k4 + 0][row] = d.x; sW[k4 + 1][row] = d.y; sW[k4 + 2][row] = d.z; sW[k4 + 3][row] = d.w;
    }
    __syncthreads();
    #pragma unroll
    for (int kk = 0; kk < 32; ++kk) {
      float mm[4], nn[4];
      #pragma unroll
      for (int q = 0; q < 4; ++q) mm[q] = sA[kk][tm * 4 + q];
      #pragma unroll
      for (int q = 0; q < 4; ++q) nn[q] = sW[kk][tn * 4 + q];
      #pragma unroll
      for (int r = 0; r < 4; ++r)
        #pragma unroll
        for (int c = 0; c < 4; ++c)
          acc[r][c] = fmaf(mm[r], nn[c], acc[r][c]);
    }
    __syncthreads();
  }
  #pragma unroll
  for (int r = 0; r < 4; ++r) {
    int bb = b0 + tm * 4 + r;
    float4 v = make_float4(acc[r][0] + bias[o0 + tn * 4 + 0],
                           acc[r][1] + bias[o0 + tn * 4 + 1],
                           acc[r][2] + bias[o0 + tn * 4 + 2],
                           acc[r][3] + bias[o0 + tn * 4 + 3]);
    *(float4*)&y[bb * 128 + o0 + tn * 4] = v;
  }
}

extern "C" void kernel_launch(void* const* d_in, const int* in_sizes, int n_in,
                              void* d_out, int out_size, void* d_ws, size_t ws_size,
                              hipStream_t stream) {
  const float* u   = (const float*)d_in[0];
  const float* X   = (const float*)d_in[1];
  const float* Y   = (const float*)d_in[2];
  const float* B2  = (const float*)d_in[3];
  const float* C2  = (const float*)d_in[4];
  const float* D21 = (const float*)d_in[5];
  const float* D22 = (const float*)d_in[6];
  const float* D12 = (const float*)d_in[7];
  const float* x0  = (const float*)d_in[8];

  float* ws = (float*)d_ws;
  float* H     = ws;                    // 1327104
  float* M     = H + 1327104;           // 512*640 = 327680
  float* Gt    = M + 327680;            // 65536
  float* W1    = Gt + 65536;            // 16384
  float* W2    = W1 + 16384;            // 16384
  float* D11   = W2 + 16384;            // 16384
  float* Lam   = D11 + 16384;           // 128
  float* xc    = Lam + 128;             // 128
  float* Fx    = xc + 128;              // 512
  float* bias  = Fx + 512;              // 128
  int*   flags = (int*)(bias + 128);    // [0..7]=bs flags, [16..23]=LU panel counts
  float* baseT = bias + 128 + 64;       // 128*16384 = 2097152
  float* wT    = baseT;                 // in-place
  // Dfac aliases the dead H11 region (rows 0..511, cols 0..511 of H are only read by k_assemble,
  // which is stream-ordered before the LU). 8 * 64*64 = 32768 floats.
  float* Dfac  = H;
  float* y     = (float*)d_out;

  k_xtx<<<dim3(18, 18), 256, 0, stream>>>(X, H);
  k_assemble<<<389, 256, 0, stream>>>(H, Y, C2, x0, M, D11, Lam, xc, Fx, flags);

  for (int kb = 0; kb < 8; ++kb) {
    int npan = 16 - 2 * kb;
    int ntr = (kb < 7) ? (9 - kb) * (7 - kb) : 0;
    k_lu_step<<<npan + ntr, 256, 0, stream>>>(M, Dfac, kb, flags + 16 + kb);
  }

  k_bs<<<8, 512, 0, stream>>>(M, Dfac, Gt, flags);
  k_wass<<<129, 256, 0, stream>>>(Gt, H, B2, D21, D22, Fx, W1, W2, bias);

  k_ud<<<dim3(256, 2), 256, 0, stream>>>(u, D12, xc, baseT);
  k_scan<<<256, 64, 0, stream>>>(baseT, D11, Lam, wT);
  k_y<<<dim3(256, 2), 256, 0, stream>>>(wT, u, W1, W2, bias, y);
}

// Round 5
// 1184.144 us; speedup vs baseline: 1.6643x; 1.6643x over previous
//
#include <hip/hip_runtime.h>
#include <math.h>

#define EPS_C 0.001f
#define BATCH 16384
#define FLAG_SIG 0x600D0000

// ---------------- H = X^T X + eps*I  (1152x1152), symmetric: compute bi<=bj, mirror ----------------
__global__ __launch_bounds__(256) void k_xtx(const float* __restrict__ X, float* __restrict__ H) {
  __shared__ float smem[64 * 65];
  const int bi64 = blockIdx.x, bj64 = blockIdx.y;
  if (bi64 > bj64) return;
  float (*sA)[65] = (float(*)[65])smem;
  float (*sB)[65] = (float(*)[65])(smem + 32 * 65);
  const int t = threadIdx.x;
  const int bi = bi64 * 64, bj = bj64 * 64;
  const int tj = t & 15, ti = t >> 4;
  float acc[4][4] = {};
  for (int k0 = 0; k0 < 1152; k0 += 32) {
    #pragma unroll
    for (int l = 0; l < 2; ++l) {
      int idx = t + l * 256;
      int kk = idx >> 4, c4 = (idx & 15) << 2;
      float4 va = *(const float4*)&X[(k0 + kk) * 1152 + bi + c4];
      sA[kk][c4 + 0] = va.x; sA[kk][c4 + 1] = va.y; sA[kk][c4 + 2] = va.z; sA[kk][c4 + 3] = va.w;
      float4 vb = *(const float4*)&X[(k0 + kk) * 1152 + bj + c4];
      sB[kk][c4 + 0] = vb.x; sB[kk][c4 + 1] = vb.y; sB[kk][c4 + 2] = vb.z; sB[kk][c4 + 3] = vb.w;
    }
    __syncthreads();
    #pragma unroll
    for (int kk = 0; kk < 32; ++kk) {
      float am[4], bn[4];
      #pragma unroll
      for (int q = 0; q < 4; ++q) am[q] = sA[kk][ti * 4 + q];
      #pragma unroll
      for (int q = 0; q < 4; ++q) bn[q] = sB[kk][tj * 4 + q];
      #pragma unroll
      for (int r = 0; r < 4; ++r)
        #pragma unroll
        for (int c = 0; c < 4; ++c)
          acc[r][c] = fmaf(am[r], bn[c], acc[r][c]);
    }
    __syncthreads();
  }
  #pragma unroll
  for (int r = 0; r < 4; ++r) {
    int gi = bi + ti * 4 + r;
    float vv[4];
    #pragma unroll
    for (int c = 0; c < 4; ++c) {
      vv[c] = acc[r][c];
      if (gi == bj + tj * 4 + c) vv[c] += EPS_C;
    }
    float4 o = make_float4(vv[0], vv[1], vv[2], vv[3]);
    *(float4*)&H[gi * 1152 + bj + tj * 4] = o;
  }
  if (bi64 < bj64) {
    float (*tr)[65] = (float(*)[65])smem;
    #pragma unroll
    for (int r = 0; r < 4; ++r)
      #pragma unroll
      for (int c = 0; c < 4; ++c)
        tr[tj * 4 + c][ti * 4 + r] = acc[r][c];
    __syncthreads();
    #pragma unroll
    for (int l = 0; l < 4; ++l) {
      int e = t + l * 256;
      int row = e >> 4, c4 = (e & 15) << 2;
      float4 o = make_float4(tr[row][c4], tr[row][c4 + 1], tr[row][c4 + 2], tr[row][c4 + 3]);
      *(float4*)&H[(bj + row) * 1152 + bi + c4] = o;
    }
  }
}

// ---------------- assemble M=[E^T | C2^T], D11, Lam, xc, Fx; zero sync flags ----------------
__global__ __launch_bounds__(256) void k_assemble(const float* __restrict__ H, const float* __restrict__ Y,
                           const float* __restrict__ C2, const float* __restrict__ x0,
                           float* __restrict__ M, float* __restrict__ D11,
                           float* __restrict__ Lam, float* __restrict__ xc, float* __restrict__ Fx,
                           int* __restrict__ flags) {
  const int b = blockIdx.x;
  const int t = threadIdx.x;
  if (b < 256) {
    __shared__ float tA[32][33], tB[32][33], tC[32][33];
    const int R0 = (b & 15) * 32, C0 = (b >> 4) * 32;
    const int c = t & 31, rr = t >> 5;
    #pragma unroll
    for (int p = 0; p < 4; ++p) {
      int row = rr + p * 8;
      tA[row][c] = H[(C0 + row) * 1152 + R0 + c];
      tB[row][c] = H[(640 + C0 + row) * 1152 + 640 + R0 + c];
      tC[row][c] = Y[(C0 + row) * 512 + R0 + c];
    }
    __syncthreads();
    #pragma unroll
    for (int p = 0; p < 4; ++p) {
      int r = rr + p * 8;
      float val = 0.5f * (tA[c][r] + tB[c][r] + tC[c][r] - Y[(R0 + r) * 512 + C0 + c]);
      M[(R0 + r) * 640 + C0 + c] = val;
    }
  } else if (b < 320) {
    int e0 = (b - 256) * 1024;
    #pragma unroll
    for (int l = 0; l < 4; ++l) {
      int e = e0 + l * 256 + t;
      int r = e >> 7, o = e & 127;
      M[r * 640 + 512 + o] = C2[o * 512 + r];
    }
  } else if (b < 384) {
    int e = (b - 320) * 256 + t;
    int i = e >> 7, j = e & 127;
    D11[e] = (j < i) ? -H[(512 + i) * 1152 + 512 + j] : 0.0f;
  } else if (b == 384) {
    if (t < 128) Lam[t] = 0.5f * H[(512 + t) * 1152 + 512 + t];
  } else if (b == 385) {
    if (t < 128) {
      float s = 0.f;
      for (int a = 0; a < 512; ++a) s = fmaf(H[(512 + t) * 1152 + a], x0[a], s);
      xc[t] = -s;
    }
  } else if (b < 388) {
    int r = (b - 386) * 256 + t;
    float s = 0.f;
    for (int a = 0; a < 512; ++a) s = fmaf(H[(640 + r) * 1152 + a], x0[a], s);
    Fx[r] = s;
  } else {
    if (t < 32) flags[t] = 0;
  }
}

// ---------------- fused diag+panels: every block redundantly factors the 64x64 diag in registers
//                  (no inter-block sync); block 0 persists factored diag to Dfac (NOT in-place: race-free) ----------------
__global__ __launch_bounds__(64) void k_lu_dp(float* __restrict__ M, float* __restrict__ Dfac, int kb) {
  __shared__ float sD[64 * 65];
  __shared__ float sRD[64];
  const int t = threadIdx.x;
  const int nU = 9 - kb;
  const int pb = blockIdx.x;
  // issue panel loads early (panel strips are untouched by the diag factor)
  float v[64];
  int c = 0, rr = 0;
  if (pb < nU) {
    c = 64 * (kb + 1) + pb * 64 + t;
    #pragma unroll
    for (int i = 0; i < 64; ++i) v[i] = M[(kb * 64 + i) * 640 + c];
  } else {
    rr = 64 * (kb + 1) + (pb - nU) * 64 + t;
    #pragma unroll
    for (int i = 0; i < 16; ++i) *(float4*)&v[i * 4] = *(const float4*)&M[rr * 640 + kb * 64 + i * 4];
  }
  // redundant in-register LU factor of diag (reads ORIGINAL M diag; M's diag is never overwritten)
  {
    const float* blk = M + kb * 64 * 640 + kb * 64;
    float col[64];
    #pragma unroll
    for (int r = 0; r < 64; ++r) col[r] = blk[r * 640 + t];
    float invp = 1.0f;
    #pragma unroll
    for (int k = 0; k < 64; ++k) {
      float piv = __shfl(col[k], k);
      float inv = 1.0f / piv;
      if (t == k) invp = inv;
      float m = col[k] * inv;
      bool act = t > k;
      #pragma unroll
      for (int r = k + 1; r < 64; ++r) {
        float ckr = __shfl(col[r], k);
        if (act) col[r] -= ckr * m;
      }
    }
    #pragma unroll
    for (int r = 0; r < 64; ++r) {
      if (r > t) col[r] *= invp;
      sD[r * 65 + t] = col[r];
      if (pb == 0) Dfac[kb * 4096 + r * 64 + t] = col[r];
    }
    sRD[t] = invp;  // == 1/sD[t*65+t] bitwise
  }
  __syncthreads();
  if (pb < nU) {
    #pragma unroll
    for (int i = 1; i < 64; ++i) {
      float a0 = v[i], a1 = 0.f;
      #pragma unroll
      for (int j = 0; j < i; j += 2) {
        a0 = fmaf(-sD[i * 65 + j], v[j], a0);
        if (j + 1 < i) a1 = fmaf(-sD[i * 65 + j + 1], v[j + 1], a1);
      }
      v[i] = a0 + a1;
    }
    #pragma unroll
    for (int i = 0; i < 64; ++i) M[(kb * 64 + i) * 640 + c] = v[i];
  } else {
    #pragma unroll
    for (int j = 0; j < 64; ++j) {
      float a0 = v[j], a1 = 0.f;
      #pragma unroll
      for (int i = 0; i < j; i += 2) {
        a0 = fmaf(-v[i], sD[i * 65 + j], a0);
        if (i + 1 < j) a1 = fmaf(-v[i + 1], sD[(i + 1) * 65 + j], a1);
      }
      v[j] = (a0 + a1) * sRD[j];
    }
    #pragma unroll
    for (int i = 0; i < 16; ++i) *(float4*)&M[rr * 640 + kb * 64 + i * 4] = *(float4*)&v[i * 4];
  }
}

// ---------------- trailing update: A22 -= L21 * U12 (cols include augmented) ----------------
__global__ __launch_bounds__(256) void k_lu_trailing(float* __restrict__ M, int kb) {
  __shared__ float sL[32][65];
  __shared__ float sU[32][65];
  const int t = threadIdx.x;
  const int base = 64 * (kb + 1);
  const int r0 = base + blockIdx.y * 64, c0 = base + blockIdx.x * 64;
  const int tj = t & 15, ti = t >> 4;
  float acc[4][4] = {};
  for (int k0 = 0; k0 < 64; k0 += 32) {
    #pragma unroll
    for (int l = 0; l < 2; ++l) {
      int idx = t + l * 256;
      int row = idx >> 3, k4 = (idx & 7) << 2;
      float4 v = *(const float4*)&M[(r0 + row) * 640 + kb * 64 + k0 + k4];
      sL[k4 + 0][row] = v.x; sL[k4 + 1][row] = v.y; sL[k4 + 2][row] = v.z; sL[k4 + 3][row] = v.w;
      int kk = idx >> 4, c4 = (idx & 15) << 2;
      float4 u4 = *(const float4*)&M[(kb * 64 + k0 + kk) * 640 + c0 + c4];
      sU[kk][c4 + 0] = u4.x; sU[kk][c4 + 1] = u4.y; sU[kk][c4 + 2] = u4.z; sU[kk][c4 + 3] = u4.w;
    }
    __syncthreads();
    #pragma unroll
    for (int kk = 0; kk < 32; ++kk) {
      float am[4], bn[4];
      #pragma unroll
      for (int q = 0; q < 4; ++q) am[q] = sL[kk][ti * 4 + q];
      #pragma unroll
      for (int q = 0; q < 4; ++q) bn[q] = sU[kk][tj * 4 + q];
      #pragma unroll
      for (int r = 0; r < 4; ++r)
        #pragma unroll
        for (int c = 0; c < 4; ++c)
          acc[r][c] = fmaf(am[r], bn[c], acc[r][c]);
    }
    __syncthreads();
  }
  #pragma unroll
  for (int r = 0; r < 4; ++r) {
    float4 old = *(float4*)&M[(r0 + ti * 4 + r) * 640 + c0 + tj * 4];
    old.x -= acc[r][0]; old.y -= acc[r][1]; old.z -= acc[r][2]; old.w -= acc[r][3];
    *(float4*)&M[(r0 + ti * 4 + r) * 640 + c0 + tj * 4] = old;
  }
}

// ---------------- invert each factored 64x64 diag block: invU[kb] = U_kk^-1 (8 parallel blocks,
//                  64-thread blocks so v[64] stays in registers; off the k_bs critical chain) ----------------
__global__ __launch_bounds__(64) void k_inv(const float* __restrict__ Dfac, float* __restrict__ invU) {
  __shared__ float sD[64 * 65];
  __shared__ float srs[64];
  const int t = threadIdx.x;
  const int kb = blockIdx.x;
  for (int l = 0; l < 64; ++l) sD[l * 65 + t] = Dfac[kb * 4096 + l * 64 + t];
  __syncthreads();
  srs[t] = 1.0f / sD[t * 65 + t];
  __syncthreads();
  // column t of U^-1 via back-substitution, fully unrolled, registers only
  float v[64];
  #pragma unroll
  for (int i = 0; i < 64; ++i) v[i] = (i == t) ? srs[t] : 0.0f;
  #pragma unroll
  for (int i = 62; i >= 0; --i) {
    float a0 = 0.f, a1 = 0.f;
    #pragma unroll
    for (int j = i + 1; j < 64; j += 2) {
      a0 = fmaf(-sD[i * 65 + j], v[j], a0);
      if (j + 1 < 64) a1 = fmaf(-sD[i * 65 + j + 1], v[j + 1], a1);
    }
    float nv = (a0 + a1) * srs[i];
    v[i] = (i == t) ? v[i] : nv;   // nv==0 naturally for i>t (strictly-upper zeros)
  }
  #pragma unroll
  for (int i = 0; i < 64; ++i) invU[kb * 4096 + i * 64 + t] = v[i];
}

// ---------------- backward solve U * Gt = Z : 8 blocks, relaxed-poll chained;
//                  final per-block solve = invU GEMM (no serial chain, no spills) ----------------
__global__ __launch_bounds__(512) void k_bs(float* __restrict__ M, const float* __restrict__ invUg,
                                            float* __restrict__ Gt, int* __restrict__ flags) {
  __shared__ float sU[64 * 65];
  __shared__ float sX[64 * 128];
  __shared__ float sI[64 * 64];
  const int kb = blockIdx.x;       // row block owned
  const int t = threadIdx.x;
  const int o = t & 127, q = t >> 7;
  float z[16];
  #pragma unroll
  for (int r = 0; r < 16; ++r) z[r] = M[(kb * 64 + q * 16 + r) * 640 + 512 + o];
  // stage this block's invU once, up front (ready at launch; hides under the whole wait chain)
  #pragma unroll
  for (int l = 0; l < 8; ++l) {
    int e = t + l * 512;
    sI[e] = invUg[kb * 4096 + e];
  }

  for (int j = 7; j > kb; --j) {
    // prestage U_{kb,j} (ready at launch) -- overlaps the flag wait
    #pragma unroll
    for (int l = 0; l < 8; ++l) {
      int e = t + l * 512;
      int r = e >> 6, k = e & 63;
      sU[r * 65 + k] = M[(kb * 64 + r) * 640 + j * 64 + k];
    }
    if (t == 0) {
      while (__hip_atomic_load(&flags[j], __ATOMIC_RELAXED, __HIP_MEMORY_SCOPE_AGENT) != (FLAG_SIG + j))
        __builtin_amdgcn_s_sleep(1);
      (void)__hip_atomic_load(&flags[j], __ATOMIC_ACQUIRE, __HIP_MEMORY_SCOPE_AGENT);
    }
    __syncthreads();
    #pragma unroll
    for (int l = 0; l < 16; ++l) {
      int e = t + l * 512;
      int k = e >> 7, o2 = e & 127;
      sX[k * 128 + o2] = Gt[(j * 64 + k) * 128 + o2];
    }
    __syncthreads();
    for (int k = 0; k < 64; ++k) {
      float xk = sX[k * 128 + o];
      #pragma unroll
      for (int r = 0; r < 16; ++r)
        z[r] = fmaf(-sU[(q * 16 + r) * 65 + k], xk, z[r]);
    }
    __syncthreads();
  }

  // dump z to LDS, then x = invU @ z as a parallel GEMM (512 threads, 16 rows each)
  #pragma unroll
  for (int r = 0; r < 16; ++r) sX[(q * 16 + r) * 128 + o] = z[r];
  __syncthreads();
  #pragma unroll
  for (int r = 0; r < 16; ++r) {
    int i = q * 16 + r;
    float a0 = 0.f, a1 = 0.f;
    #pragma unroll
    for (int k = 0; k < 64; k += 2) {
      a0 = fmaf(sI[i * 64 + k], sX[k * 128 + o], a0);
      a1 = fmaf(sI[i * 64 + k + 1], sX[(k + 1) * 128 + o], a1);
    }
    Gt[(kb * 64 + i) * 128 + o] = a0 + a1;
  }
  __threadfence();
  __syncthreads();
  if (t == 0)
    __hip_atomic_store(&flags[kb], FLAG_SIG + kb, __ATOMIC_RELEASE, __HIP_MEMORY_SCOPE_AGENT);
}

// ---------------- W1 = G@B1 + D21, W2 = G@B2 + D22, bias = G@Fx ----------------
__global__ void k_wass(const float* __restrict__ Gt, const float* __restrict__ H,
                       const float* __restrict__ B2, const float* __restrict__ D21,
                       const float* __restrict__ D22, const float* __restrict__ Fx,
                       float* __restrict__ W1, float* __restrict__ W2, float* __restrict__ bias) {
  int idx = blockIdx.x * 256 + threadIdx.x;
  if (idx < 16384) {
    int o = idx >> 7, j = idx & 127;
    float s = 0.f;
    for (int a = 0; a < 512; ++a) s = fmaf(Gt[a * 128 + o], H[(640 + a) * 1152 + 512 + j], s);
    W1[idx] = s + D21[idx];
  } else if (idx < 32768) {
    int q = idx - 16384;
    int o = q >> 7, j = q & 127;
    float s = 0.f;
    for (int a = 0; a < 512; ++a) s = fmaf(Gt[a * 128 + o], B2[a * 128 + j], s);
    W2[q] = s + D22[q];
  } else if (idx < 32768 + 128) {
    int o = idx - 32768;
    float s = 0.f;
    for (int a = 0; a < 512; ++a) s = fmaf(Gt[a * 128 + o], Fx[a], s);
    bias[o] = s;
  }
}

// ---------------- baseT[i][b] = xc[i] + (u @ D12^T)[b][i] ----------------
__global__ __launch_bounds__(256) void k_ud(const float* __restrict__ u, const float* __restrict__ D12,
                                            const float* __restrict__ xc, float* __restrict__ baseT) {
  __shared__ float sU[32][65];
  __shared__ float sD[32][65];
  const int t = threadIdx.x;
  const int b0 = blockIdx.x * 64, i0 = blockIdx.y * 64;
  const int tm = t & 15, tn = t >> 4;
  float acc[4][4] = {};
  for (int k0 = 0; k0 < 128; k0 += 32) {
    #pragma unroll
    for (int l = 0; l < 2; ++l) {
      int idx = t + l * 256;
      int row = idx >> 3, k4 = (idx & 7) << 2;
      float4 v = *(const float4*)&u[(b0 + row) * 128 + k0 + k4];
      sU[k4 + 0][row] = v.x; sU[k4 + 1][row] = v.y; sU[k4 + 2][row] = v.z; sU[k4 + 3][row] = v.w;
      float4 d = *(const float4*)&D12[(i0 + row) * 128 + k0 + k4];
      sD[k4 + 0][row] = d.x; sD[k4 + 1][row] = d.y; sD[k4 + 2][row] = d.z; sD[k4 + 3][row] = d.w;
    }
    __syncthreads();
    #pragma unroll
    for (int kk = 0; kk < 32; ++kk) {
      float mm[4], nn[4];
      #pragma unroll
      for (int q = 0; q < 4; ++q) mm[q] = sU[kk][tm * 4 + q];
      #pragma unroll
      for (int q = 0; q < 4; ++q) nn[q] = sD[kk][tn * 4 + q];
      #pragma unroll
      for (int c = 0; c < 4; ++c)
        #pragma unroll
        for (int r = 0; r < 4; ++r)
          acc[c][r] = fmaf(nn[c], mm[r], acc[c][r]);
    }
    __syncthreads();
  }
  #pragma unroll
  for (int c = 0; c < 4; ++c) {
    int i = i0 + tn * 4 + c;
    float xcv = xc[i];
    float4 v = make_float4(acc[c][0] + xcv, acc[c][1] + xcv, acc[c][2] + xcv, acc[c][3] + xcv);
    *(float4*)&baseT[i * BATCH + b0 + tm * 4] = v;
  }
}

// ---------------- scan: w[i] = tanh((base_i + sum_{j<i} D11[i][j] w[j]) / Lam[i]) ----------------
__global__ __launch_bounds__(64) void k_scan(const float* __restrict__ baseT, const float* __restrict__ D11g,
                                             const float* __restrict__ Lam, float* __restrict__ wT) {
  const int b = blockIdx.x * 64 + threadIdx.x;
  float w[128];
  #pragma unroll
  for (int i = 0; i < 128; ++i) {
    float acc0 = baseT[i * BATCH + b], acc1 = 0.f, acc2 = 0.f, acc3 = 0.f;
    const float* __restrict__ Drow = D11g + i * 128;
    #pragma unroll
    for (int j = 0; j + 4 <= i; j += 4) {
      acc0 = fmaf(w[j + 0], Drow[j + 0], acc0);
      acc1 = fmaf(w[j + 1], Drow[j + 1], acc1);
      acc2 = fmaf(w[j + 2], Drow[j + 2], acc2);
      acc3 = fmaf(w[j + 3], Drow[j + 3], acc3);
    }
    #pragma unroll
    for (int j = i & ~3; j < i; ++j) acc0 = fmaf(w[j], Drow[j], acc0);
    float zv = ((acc0 + acc1) + (acc2 + acc3)) / Lam[i];
    float az = fabsf(zv);
    float e = __expf(-2.0f * az);
    float th = (1.0f - e) / (1.0f + e);
    w[i] = copysignf(th, zv);
    wT[i * BATCH + b] = w[i];
  }
}

// ---------------- y = w@W1^T + u@W2^T + bias ----------------
__global__ __launch_bounds__(256) void k_y(const float* __restrict__ wT, const float* __restrict__ u,
                                           const float* __restrict__ W1, const float* __restrict__ W2,
                                           const float* __restrict__ bias, float* __restrict__ y) {
  __shared__ float sA[32][65];
  __shared__ float sW[32][65];
  const int t = threadIdx.x;
  const int b0 = blockIdx.x * 64, o0 = blockIdx.y * 64;
  const int tn = t & 15, tm = t >> 4;
  float acc[4][4] = {};
  for (int k0 = 0; k0 < 128; k0 += 32) {
    #pragma unroll
    for (int l = 0; l < 2; ++l) {
      int idx = t + l * 256;
      int kk = idx >> 4, c4 = (idx & 15) << 2;
      float4 v = *(const float4*)&wT[(k0 + kk) * BATCH + b0 + c4];
      sA[kk][c4 + 0] = v.x; sA[kk][c4 + 1] = v.y; sA[kk][c4 + 2] = v.z; sA[kk][c4 + 3] = v.w;
      int row = idx >> 3, k4 = (idx & 7) << 2;
      float4 d = *(const float4*)&W1[(o0 + row) * 128 + k0 + k4];
      sW[k4 + 0][row] = d.x; sW[k4 + 1][row] = d.y; sW[k4 + 2][row] = d.z; sW[k4 + 3][row] = d.w;
    }
    __syncthreads();
    #pragma unroll
    for (int kk = 0; kk < 32; ++kk) {
      float mm[4], nn[4];
      #pragma unroll
      for (int q = 0; q < 4; ++q) mm[q] = sA[kk][tm * 4 + q];
      #pragma unroll
      for (int q = 0; q < 4; ++q) nn[q] = sW[kk][tn * 4 + q];
      #pragma unroll
      for (int r = 0; r < 4; ++r)
        #pragma unroll
        for (int c = 0; c < 4; ++c)
          acc[r][c] = fmaf(mm[r], nn[c], acc[r][c]);
    }
    __syncthreads();
  }
  for (int k0 = 0; k0 < 128; k0 += 32) {
    #pragma unroll
    for (int l = 0; l < 2; ++l) {
      int idx = t + l * 256;
      int row = idx >> 3, k4 = (idx & 7) << 2;
      float4 v = *(const float4*)&u[(b0 + row) * 128 + k0 + k4];
      sA[k4 + 0][row] = v.x; sA[k4 + 1][row] = v.y; sA[k4 + 2][row] = v.z; sA[k4 + 3][row] = v.w;
      float4 d = *(const float4*)&W2[(o0 + row) * 128 + k0 + k4];
      sW[k4 + 0][row] = d.x; sW[k4 + 1][row] = d.y; sW[k4 + 2][row] = d.z; sW[k4 + 3][row] = d.w;
    }
    __syncthreads();
    #pragma unroll
    for (int kk = 0; kk < 32; ++kk) {
      float mm[4], nn[4];
      #pragma unroll
      for (int q = 0; q < 4; ++q) mm[q] = sA[kk][tm * 4 + q];
      #pragma unroll
      for (int q = 0; q < 4; ++q) nn[q] = sW[kk][tn * 4 + q];
      #pragma unroll
      for (int r = 0; r < 4; ++r)
        #pragma unroll
        for (int c = 0; c < 4; ++c)
          acc[r][c] = fmaf(mm[r], nn[c], acc[r][c]);
    }
    __syncthreads();
  }
  #pragma unroll
  for (int r = 0; r < 4; ++r) {
    int bb = b0 + tm * 4 + r;
    float4 v = make_float4(acc[r][0] + bias[o0 + tn * 4 + 0],
                           acc[r][1] + bias[o0 + tn * 4 + 1],
                           acc[r][2] + bias[o0 + tn * 4 + 2],
                           acc[r][3] + bias[o0 + tn * 4 + 3]);
    *(float4*)&y[bb * 128 + o0 + tn * 4] = v;
  }
}

extern "C" void kernel_launch(void* const* d_in, const int* in_sizes, int n_in,
                              void* d_out, int out_size, void* d_ws, size_t ws_size,
                              hipStream_t stream) {
  const float* u   = (const float*)d_in[0];
  const float* X   = (const float*)d_in[1];
  const float* Y   = (const float*)d_in[2];
  const float* B2  = (const float*)d_in[3];
  const float* C2  = (const float*)d_in[4];
  const float* D21 = (const float*)d_in[5];
  const float* D22 = (const float*)d_in[6];
  const float* D12 = (const float*)d_in[7];
  const float* x0  = (const float*)d_in[8];

  float* ws = (float*)d_ws;
  float* H     = ws;                    // 1327104
  float* M     = H + 1327104;           // 512*640 = 327680
  float* Gt    = M + 327680;            // 65536
  float* W1    = Gt + 65536;            // 16384
  float* W2    = W1 + 16384;            // 16384
  float* D11   = W2 + 16384;            // 16384
  float* Lam   = D11 + 16384;           // 128
  float* xc    = Lam + 128;             // 128
  float* Fx    = xc + 128;              // 512
  float* bias  = Fx + 512;              // 128
  int*   flags = (int*)(bias + 128);    // [0..7]=bs flags
  float* baseT = bias + 128 + 64;       // 128*16384 = 2097152
  float* wT    = baseT;                 // in-place
  // Dfac / invUg alias the dead H11 region (H rows 0..511 cols 0..511 are only read by
  // k_assemble, stream-ordered before the LU). 2 * 8 * 64*64 = 65536 floats = ~57 H-rows.
  float* Dfac  = H;
  float* invUg = H + 32768;
  float* y     = (float*)d_out;

  k_xtx<<<dim3(18, 18), 256, 0, stream>>>(X, H);
  k_assemble<<<389, 256, 0, stream>>>(H, Y, C2, x0, M, D11, Lam, xc, Fx, flags);

  for (int kb = 0; kb < 8; ++kb) {
    k_lu_dp<<<16 - 2 * kb, 64, 0, stream>>>(M, Dfac, kb);
    if (kb < 7)
      k_lu_trailing<<<dim3(9 - kb, 7 - kb), 256, 0, stream>>>(M, kb);
  }

  k_inv<<<8, 64, 0, stream>>>(Dfac, invUg);
  k_bs<<<8, 512, 0, stream>>>(M, invUg, Gt, flags);
  k_wass<<<129, 256, 0, stream>>>(Gt, H, B2, D21, D22, Fx, W1, W2, bias);

  k_ud<<<dim3(256, 2), 256, 0, stream>>>(u, D12, xc, baseT);
  k_scan<<<256, 64, 0, stream>>>(baseT, D11, Lam, wT);
  k_y<<<dim3(256, 2), 256, 0, stream>>>(wT, u, W1, W2, bias, y);
}

// Round 6
// 1135.198 us; speedup vs baseline: 1.7361x; 1.0431x over previous
//
#include <hip/hip_runtime.h>
#include <math.h>

#define EPS_C 0.001f
#define BATCH 16384

// ---------------- H = X^T X + eps*I  (1152x1152), symmetric: compute bi<=bj, mirror ----------------
__global__ __launch_bounds__(256) void k_xtx(const float* __restrict__ X, float* __restrict__ H) {
  __shared__ float smem[64 * 65];
  const int bi64 = blockIdx.x, bj64 = blockIdx.y;
  if (bi64 > bj64) return;
  float (*sA)[65] = (float(*)[65])smem;
  float (*sB)[65] = (float(*)[65])(smem + 32 * 65);
  const int t = threadIdx.x;
  const int bi = bi64 * 64, bj = bj64 * 64;
  const int tj = t & 15, ti = t >> 4;
  float acc[4][4] = {};
  for (int k0 = 0; k0 < 1152; k0 += 32) {
    #pragma unroll
    for (int l = 0; l < 2; ++l) {
      int idx = t + l * 256;
      int kk = idx >> 4, c4 = (idx & 15) << 2;
      float4 va = *(const float4*)&X[(k0 + kk) * 1152 + bi + c4];
      sA[kk][c4 + 0] = va.x; sA[kk][c4 + 1] = va.y; sA[kk][c4 + 2] = va.z; sA[kk][c4 + 3] = va.w;
      float4 vb = *(const float4*)&X[(k0 + kk) * 1152 + bj + c4];
      sB[kk][c4 + 0] = vb.x; sB[kk][c4 + 1] = vb.y; sB[kk][c4 + 2] = vb.z; sB[kk][c4 + 3] = vb.w;
    }
    __syncthreads();
    #pragma unroll
    for (int kk = 0; kk < 32; ++kk) {
      float am[4], bn[4];
      #pragma unroll
      for (int q = 0; q < 4; ++q) am[q] = sA[kk][ti * 4 + q];
      #pragma unroll
      for (int q = 0; q < 4; ++q) bn[q] = sB[kk][tj * 4 + q];
      #pragma unroll
      for (int r = 0; r < 4; ++r)
        #pragma unroll
        for (int c = 0; c < 4; ++c)
          acc[r][c] = fmaf(am[r], bn[c], acc[r][c]);
    }
    __syncthreads();
  }
  #pragma unroll
  for (int r = 0; r < 4; ++r) {
    int gi = bi + ti * 4 + r;
    float vv[4];
    #pragma unroll
    for (int c = 0; c < 4; ++c) {
      vv[c] = acc[r][c];
      if (gi == bj + tj * 4 + c) vv[c] += EPS_C;
    }
    float4 o = make_float4(vv[0], vv[1], vv[2], vv[3]);
    *(float4*)&H[gi * 1152 + bj + tj * 4] = o;
  }
  if (bi64 < bj64) {
    float (*tr)[65] = (float(*)[65])smem;
    #pragma unroll
    for (int r = 0; r < 4; ++r)
      #pragma unroll
      for (int c = 0; c < 4; ++c)
        tr[tj * 4 + c][ti * 4 + r] = acc[r][c];
    __syncthreads();
    #pragma unroll
    for (int l = 0; l < 4; ++l) {
      int e = t + l * 256;
      int row = e >> 4, c4 = (e & 15) << 2;
      float4 o = make_float4(tr[row][c4], tr[row][c4 + 1], tr[row][c4 + 2], tr[row][c4 + 3]);
      *(float4*)&H[(bj + row) * 1152 + bi + c4] = o;
    }
  }
}

// ---------------- assemble M=[E^T | C2^T], D11, Lam, xc, Fx ----------------
__global__ __launch_bounds__(256) void k_assemble(const float* __restrict__ H, const float* __restrict__ Y,
                           const float* __restrict__ C2, const float* __restrict__ x0,
                           float* __restrict__ M, float* __restrict__ D11,
                           float* __restrict__ Lam, float* __restrict__ xc, float* __restrict__ Fx) {
  const int b = blockIdx.x;
  const int t = threadIdx.x;
  if (b < 256) {
    __shared__ float tA[32][33], tB[32][33], tC[32][33];
    const int R0 = (b & 15) * 32, C0 = (b >> 4) * 32;
    const int c = t & 31, rr = t >> 5;
    #pragma unroll
    for (int p = 0; p < 4; ++p) {
      int row = rr + p * 8;
      tA[row][c] = H[(C0 + row) * 1152 + R0 + c];
      tB[row][c] = H[(640 + C0 + row) * 1152 + 640 + R0 + c];
      tC[row][c] = Y[(C0 + row) * 512 + R0 + c];
    }
    __syncthreads();
    #pragma unroll
    for (int p = 0; p < 4; ++p) {
      int r = rr + p * 8;
      float val = 0.5f * (tA[c][r] + tB[c][r] + tC[c][r] - Y[(R0 + r) * 512 + C0 + c]);
      M[(R0 + r) * 640 + C0 + c] = val;
    }
  } else if (b < 320) {
    int e0 = (b - 256) * 1024;
    #pragma unroll
    for (int l = 0; l < 4; ++l) {
      int e = e0 + l * 256 + t;
      int r = e >> 7, o = e & 127;
      M[r * 640 + 512 + o] = C2[o * 512 + r];
    }
  } else if (b < 384) {
    int e = (b - 320) * 256 + t;
    int i = e >> 7, j = e & 127;
    D11[e] = (j < i) ? -H[(512 + i) * 1152 + 512 + j] : 0.0f;
  } else if (b == 384) {
    if (t < 128) Lam[t] = 0.5f * H[(512 + t) * 1152 + 512 + t];
  } else if (b == 385) {
    if (t < 128) {
      float s = 0.f;
      for (int a = 0; a < 512; ++a) s = fmaf(H[(512 + t) * 1152 + a], x0[a], s);
      xc[t] = -s;
    }
  } else {
    int r = (b - 386) * 256 + t;
    float s = 0.f;
    for (int a = 0; a < 512; ++a) s = fmaf(H[(640 + r) * 1152 + a], x0[a], s);
    Fx[r] = s;
  }
}

// ---------------- fused diag+panels: every block redundantly factors the 64x64 diag in registers
//                  (no inter-block sync); block 0 persists factored diag to Dfac (NOT in-place: race-free) ----------------
__global__ __launch_bounds__(64) void k_lu_dp(float* __restrict__ M, float* __restrict__ Dfac, int kb) {
  __shared__ float sD[64 * 65];
  __shared__ float sRD[64];
  const int t = threadIdx.x;
  const int nU = 9 - kb;
  const int pb = blockIdx.x;
  // issue panel loads early (panel strips are untouched by the diag factor)
  float v[64];
  int c = 0, rr = 0;
  if (pb < nU) {
    c = 64 * (kb + 1) + pb * 64 + t;
    #pragma unroll
    for (int i = 0; i < 64; ++i) v[i] = M[(kb * 64 + i) * 640 + c];
  } else {
    rr = 64 * (kb + 1) + (pb - nU) * 64 + t;
    #pragma unroll
    for (int i = 0; i < 16; ++i) *(float4*)&v[i * 4] = *(const float4*)&M[rr * 640 + kb * 64 + i * 4];
  }
  // redundant in-register LU factor of diag (reads ORIGINAL M diag; M's diag is never overwritten)
  {
    const float* blk = M + kb * 64 * 640 + kb * 64;
    float col[64];
    #pragma unroll
    for (int r = 0; r < 64; ++r) col[r] = blk[r * 640 + t];
    float invp = 1.0f;
    #pragma unroll
    for (int k = 0; k < 64; ++k) {
      float piv = __shfl(col[k], k);
      float inv = 1.0f / piv;
      if (t == k) invp = inv;
      float m = col[k] * inv;
      bool act = t > k;
      #pragma unroll
      for (int r = k + 1; r < 64; ++r) {
        float ckr = __shfl(col[r], k);
        if (act) col[r] -= ckr * m;
      }
    }
    #pragma unroll
    for (int r = 0; r < 64; ++r) {
      if (r > t) col[r] *= invp;
      sD[r * 65 + t] = col[r];
      if (pb == 0) Dfac[kb * 4096 + r * 64 + t] = col[r];
    }
    sRD[t] = invp;  // == 1/sD[t*65+t] bitwise
  }
  __syncthreads();
  if (pb < nU) {
    #pragma unroll
    for (int i = 1; i < 64; ++i) {
      float a0 = v[i], a1 = 0.f;
      #pragma unroll
      for (int j = 0; j < i; j += 2) {
        a0 = fmaf(-sD[i * 65 + j], v[j], a0);
        if (j + 1 < i) a1 = fmaf(-sD[i * 65 + j + 1], v[j + 1], a1);
      }
      v[i] = a0 + a1;
    }
    #pragma unroll
    for (int i = 0; i < 64; ++i) M[(kb * 64 + i) * 640 + c] = v[i];
  } else {
    #pragma unroll
    for (int j = 0; j < 64; ++j) {
      float a0 = v[j], a1 = 0.f;
      #pragma unroll
      for (int i = 0; i < j; i += 2) {
        a0 = fmaf(-v[i], sD[i * 65 + j], a0);
        if (i + 1 < j) a1 = fmaf(-v[i + 1], sD[(i + 1) * 65 + j], a1);
      }
      v[j] = (a0 + a1) * sRD[j];
    }
    #pragma unroll
    for (int i = 0; i < 16; ++i) *(float4*)&M[rr * 640 + kb * 64 + i * 4] = *(float4*)&v[i * 4];
  }
}

// ---------------- trailing update: A22 -= L21 * U12 (cols include augmented) ----------------
__global__ __launch_bounds__(256) void k_lu_trailing(float* __restrict__ M, int kb) {
  __shared__ float sL[32][65];
  __shared__ float sU[32][65];
  const int t = threadIdx.x;
  const int base = 64 * (kb + 1);
  const int r0 = base + blockIdx.y * 64, c0 = base + blockIdx.x * 64;
  const int tj = t & 15, ti = t >> 4;
  float acc[4][4] = {};
  for (int k0 = 0; k0 < 64; k0 += 32) {
    #pragma unroll
    for (int l = 0; l < 2; ++l) {
      int idx = t + l * 256;
      int row = idx >> 3, k4 = (idx & 7) << 2;
      float4 v = *(const float4*)&M[(r0 + row) * 640 + kb * 64 + k0 + k4];
      sL[k4 + 0][row] = v.x; sL[k4 + 1][row] = v.y; sL[k4 + 2][row] = v.z; sL[k4 + 3][row] = v.w;
      int kk = idx >> 4, c4 = (idx & 15) << 2;
      float4 u4 = *(const float4*)&M[(kb * 64 + k0 + kk) * 640 + c0 + c4];
      sU[kk][c4 + 0] = u4.x; sU[kk][c4 + 1] = u4.y; sU[kk][c4 + 2] = u4.z; sU[kk][c4 + 3] = u4.w;
    }
    __syncthreads();
    #pragma unroll
    for (int kk = 0; kk < 32; ++kk) {
      float am[4], bn[4];
      #pragma unroll
      for (int q = 0; q < 4; ++q) am[q] = sL[kk][ti * 4 + q];
      #pragma unroll
      for (int q = 0; q < 4; ++q) bn[q] = sU[kk][tj * 4 + q];
      #pragma unroll
      for (int r = 0; r < 4; ++r)
        #pragma unroll
        for (int c = 0; c < 4; ++c)
          acc[r][c] = fmaf(am[r], bn[c], acc[r][c]);
    }
    __syncthreads();
  }
  #pragma unroll
  for (int r = 0; r < 4; ++r) {
    float4 old = *(float4*)&M[(r0 + ti * 4 + r) * 640 + c0 + tj * 4];
    old.x -= acc[r][0]; old.y -= acc[r][1]; old.z -= acc[r][2]; old.w -= acc[r][3];
    *(float4*)&M[(r0 + ti * 4 + r) * 640 + c0 + tj * 4] = old;
  }
}

// ---------------- invert each factored 64x64 diag block: invU[kb] = U_kk^-1 (8 parallel blocks) ----------------
__global__ __launch_bounds__(64) void k_inv(const float* __restrict__ Dfac, float* __restrict__ invU) {
  __shared__ float sD[64 * 65];
  __shared__ float srs[64];
  const int t = threadIdx.x;
  const int kb = blockIdx.x;
  for (int l = 0; l < 64; ++l) sD[l * 65 + t] = Dfac[kb * 4096 + l * 64 + t];
  __syncthreads();
  srs[t] = 1.0f / sD[t * 65 + t];
  __syncthreads();
  // column t of U^-1 via back-substitution, fully unrolled, registers only
  float v[64];
  #pragma unroll
  for (int i = 0; i < 64; ++i) v[i] = (i == t) ? srs[t] : 0.0f;
  #pragma unroll
  for (int i = 62; i >= 0; --i) {
    float a0 = 0.f, a1 = 0.f;
    #pragma unroll
    for (int j = i + 1; j < 64; j += 2) {
      a0 = fmaf(-sD[i * 65 + j], v[j], a0);
      if (j + 1 < 64) a1 = fmaf(-sD[i * 65 + j + 1], v[j + 1], a1);
    }
    float nv = (a0 + a1) * srs[i];
    v[i] = (i == t) ? v[i] : nv;   // nv==0 naturally for i>t (strictly-upper zeros)
  }
  #pragma unroll
  for (int i = 0; i < 64; ++i) invU[kb * 4096 + i * 64 + t] = v[i];
}

// ---------------- backward solve U * Gt = Z : 8 INDEPENDENT column-slice blocks (16 cols each).
//                  Z slice lives in LDS; diag solves are invU GEMMs; right-looking updates.
//                  ZERO inter-block synchronization -- the flag chain is gone. ----------------
__global__ __launch_bounds__(512) void k_bs(const float* __restrict__ M, const float* __restrict__ invUg,
                                            float* __restrict__ Gt) {
  __shared__ float sZ[512 * 17];     // 512 rows x 16 cols, stride 17 (bank-spread)
  __shared__ float sU[64 * 65];
  __shared__ float sI[64 * 64];
  const int t = threadIdx.x;
  const int c0 = blockIdx.x * 16;
  const int o = t & 15, q = t >> 4;  // q in [0,32): row-thread groups
  // load this block's Z slice (augmented columns of M)
  #pragma unroll
  for (int l = 0; l < 16; ++l) {
    int e = t + l * 512;
    int r = e >> 4, oo = e & 15;
    sZ[r * 17 + oo] = M[r * 640 + 512 + c0 + oo];
  }
  for (int kb = 7; kb >= 0; --kb) {
    // stage invU(kb)
    #pragma unroll
    for (int l = 0; l < 8; ++l) {
      int e = t + l * 512;
      sI[e] = invUg[kb * 4096 + e];
    }
    __syncthreads();   // covers initial sZ load (first iter) + sI staging + prior updates
    // x_kb = invU @ z_kb : read phase (same even/odd a0/a1 chain as round-5's validated GEMM)
    float xv[2];
    #pragma unroll
    for (int rr = 0; rr < 2; ++rr) {
      int i = q * 2 + rr;
      float a0 = 0.f, a1 = 0.f;
      #pragma unroll
      for (int k = 0; k < 64; k += 2) {
        a0 = fmaf(sI[i * 64 + k], sZ[(kb * 64 + k) * 17 + o], a0);
        a1 = fmaf(sI[i * 64 + k + 1], sZ[(kb * 64 + k + 1) * 17 + o], a1);
      }
      xv[rr] = a0 + a1;
    }
    __syncthreads();   // all reads of z_kb done before overwrite
    #pragma unroll
    for (int rr = 0; rr < 2; ++rr) {
      int i = q * 2 + rr;
      sZ[(kb * 64 + i) * 17 + o] = xv[rr];
      Gt[(kb * 64 + i) * 128 + c0 + o] = xv[rr];
    }
    __syncthreads();
    if (kb == 0) break;
    // hoist x_kb into registers once (each thread: its own column o)
    float xk[64];
    #pragma unroll
    for (int k = 0; k < 64; ++k) xk[k] = sZ[(kb * 64 + k) * 17 + o];
    // updates: z_i -= U(i,kb) @ x_kb for i < kb (same descending-block, ascending-k order as before)
    for (int i = 0; i < kb; ++i) {
      #pragma unroll
      for (int l = 0; l < 8; ++l) {
        int e = t + l * 512;
        int r = e >> 6, k = e & 63;
        sU[r * 65 + k] = M[(i * 64 + r) * 640 + kb * 64 + k];
      }
      __syncthreads();
      #pragma unroll
      for (int rr = 0; rr < 2; ++rr) {
        int row = q * 2 + rr;
        float acc = sZ[(i * 64 + row) * 17 + o];
        #pragma unroll 16
        for (int k = 0; k < 64; ++k)
          acc = fmaf(-sU[row * 65 + k], xk[k], acc);
        sZ[(i * 64 + row) * 17 + o] = acc;
      }
      __syncthreads();
    }
  }
}

// ---------------- W1 = G@B1 + D21, W2 = G@B2 + D22, bias = G@Fx ----------------
__global__ void k_wass(const float* __restrict__ Gt, const float* __restrict__ H,
                       const float* __restrict__ B2, const float* __restrict__ D21,
                       const float* __restrict__ D22, const float* __restrict__ Fx,
                       float* __restrict__ W1, float* __restrict__ W2, float* __restrict__ bias) {
  int idx = blockIdx.x * 256 + threadIdx.x;
  if (idx < 16384) {
    int o = idx >> 7, j = idx & 127;
    float s = 0.f;
    for (int a = 0; a < 512; ++a) s = fmaf(Gt[a * 128 + o], H[(640 + a) * 1152 + 512 + j], s);
    W1[idx] = s + D21[idx];
  } else if (idx < 32768) {
    int q = idx - 16384;
    int o = q >> 7, j = q & 127;
    float s = 0.f;
    for (int a = 0; a < 512; ++a) s = fmaf(Gt[a * 128 + o], B2[a * 128 + j], s);
    W2[q] = s + D22[q];
  } else if (idx < 32768 + 128) {
    int o = idx - 32768;
    float s = 0.f;
    for (int a = 0; a < 512; ++a) s = fmaf(Gt[a * 128 + o], Fx[a], s);
    bias[o] = s;
  }
}

// ---------------- baseT[i][b] = xc[i] + (u @ D12^T)[b][i] ----------------
__global__ __launch_bounds__(256) void k_ud(const float* __restrict__ u, const float* __restrict__ D12,
                                            const float* __restrict__ xc, float* __restrict__ baseT) {
  __shared__ float sU[32][65];
  __shared__ float sD[32][65];
  const int t = threadIdx.x;
  const int b0 = blockIdx.x * 64, i0 = blockIdx.y * 64;
  const int tm = t & 15, tn = t >> 4;
  float acc[4][4] = {};
  for (int k0 = 0; k0 < 128; k0 += 32) {
    #pragma unroll
    for (int l = 0; l < 2; ++l) {
      int idx = t + l * 256;
      int row = idx >> 3, k4 = (idx & 7) << 2;
      float4 v = *(const float4*)&u[(b0 + row) * 128 + k0 + k4];
      sU[k4 + 0][row] = v.x; sU[k4 + 1][row] = v.y; sU[k4 + 2][row] = v.z; sU[k4 + 3][row] = v.w;
      float4 d = *(const float4*)&D12[(i0 + row) * 128 + k0 + k4];
      sD[k4 + 0][row] = d.x; sD[k4 + 1][row] = d.y; sD[k4 + 2][row] = d.z; sD[k4 + 3][row] = d.w;
    }
    __syncthreads();
    #pragma unroll
    for (int kk = 0; kk < 32; ++kk) {
      float mm[4], nn[4];
      #pragma unroll
      for (int q = 0; q < 4; ++q) mm[q] = sU[kk][tm * 4 + q];
      #pragma unroll
      for (int q = 0; q < 4; ++q) nn[q] = sD[kk][tn * 4 + q];
      #pragma unroll
      for (int c = 0; c < 4; ++c)
        #pragma unroll
        for (int r = 0; r < 4; ++r)
          acc[c][r] = fmaf(nn[c], mm[r], acc[c][r]);
    }
    __syncthreads();
  }
  #pragma unroll
  for (int c = 0; c < 4; ++c) {
    int i = i0 + tn * 4 + c;
    float xcv = xc[i];
    float4 v = make_float4(acc[c][0] + xcv, acc[c][1] + xcv, acc[c][2] + xcv, acc[c][3] + xcv);
    *(float4*)&baseT[i * BATCH + b0 + tm * 4] = v;
  }
}

// ---------------- scan: w[i] = tanh((base_i + sum_{j<i} D11[i][j] w[j]) / Lam[i]) ----------------
__global__ __launch_bounds__(64) void k_scan(const float* __restrict__ baseT, const float* __restrict__ D11g,
                                             const float* __restrict__ Lam, float* __restrict__ wT) {
  const int b = blockIdx.x * 64 + threadIdx.x;
  float w[128];
  #pragma unroll
  for (int i = 0; i < 128; ++i) {
    float acc0 = baseT[i * BATCH + b], acc1 = 0.f, acc2 = 0.f, acc3 = 0.f;
    const float* __restrict__ Drow = D11g + i * 128;
    #pragma unroll
    for (int j = 0; j + 4 <= i; j += 4) {
      acc0 = fmaf(w[j + 0], Drow[j + 0], acc0);
      acc1 = fmaf(w[j + 1], Drow[j + 1], acc1);
      acc2 = fmaf(w[j + 2], Drow[j + 2], acc2);
      acc3 = fmaf(w[j + 3], Drow[j + 3], acc3);
    }
    #pragma unroll
    for (int j = i & ~3; j < i; ++j) acc0 = fmaf(w[j], Drow[j], acc0);
    float zv = ((acc0 + acc1) + (acc2 + acc3)) / Lam[i];
    float az = fabsf(zv);
    float e = __expf(-2.0f * az);
    float th = (1.0f - e) / (1.0f + e);
    w[i] = copysignf(th, zv);
    wT[i * BATCH + b] = w[i];
  }
}

// ---------------- y = w@W1^T + u@W2^T + bias ----------------
__global__ __launch_bounds__(256) void k_y(const float* __restrict__ wT, const float* __restrict__ u,
                                           const float* __restrict__ W1, const float* __restrict__ W2,
                                           const float* __restrict__ bias, float* __restrict__ y) {
  __shared__ float sA[32][65];
  __shared__ float sW[32][65];
  const int t = threadIdx.x;
  const int b0 = blockIdx.x * 64, o0 = blockIdx.y * 64;
  const int tn = t & 15, tm = t >> 4;
  float acc[4][4] = {};
  for (int k0 = 0; k0 < 128; k0 += 32) {
    #pragma unroll
    for (int l = 0; l < 2; ++l) {
      int idx = t + l * 256;
      int kk = idx >> 4, c4 = (idx & 15) << 2;
      float4 v = *(const float4*)&wT[(k0 + kk) * BATCH + b0 + c4];
      sA[kk][c4 + 0] = v.x; sA[kk][c4 + 1] = v.y; sA[kk][c4 + 2] = v.z; sA[kk][c4 + 3] = v.w;
      int row = idx >> 3, k4 = (idx & 7) << 2;
      float4 d = *(const float4*)&W1[(o0 + row) * 128 + k0 + k4];
      sW[k4 + 0][row] = d.x; sW[k4 + 1][row] = d.y; sW[k4 + 2][row] = d.z; sW[k4 + 3][row] = d.w;
    }
    __syncthreads();
    #pragma unroll
    for (int kk = 0; kk < 32; ++kk) {
      float mm[4], nn[4];
      #pragma unroll
      for (int q = 0; q < 4; ++q) mm[q] = sA[kk][tm * 4 + q];
      #pragma unroll
      for (int q = 0; q < 4; ++q) nn[q] = sW[kk][tn * 4 + q];
      #pragma unroll
      for (int r = 0; r < 4; ++r)
        #pragma unroll
        for (int c = 0; c < 4; ++c)
          acc[r][c] = fmaf(mm[r], nn[c], acc[r][c]);
    }
    __syncthreads();
  }
  for (int k0 = 0; k0 < 128; k0 += 32) {
    #pragma unroll
    for (int l = 0; l < 2; ++l) {
      int idx = t + l * 256;
      int row = idx >> 3, k4 = (idx & 7) << 2;
      float4 v = *(const float4*)&u[(b0 + row) * 128 + k0 + k4];
      sA[k4 + 0][row] = v.x; sA[k4 + 1][row] = v.y; sA[k4 + 2][row] = v.z; sA[k4 + 3][row] = v.w;
      float4 d = *(const float4*)&W2[(o0 + row) * 128 + k0 + k4];
      sW[k4 + 0][row] = d.x; sW[k4 + 1][row] = d.y; sW[k4 + 2][row] = d.z; sW[k4 + 3][row] = d.w;
    }
    __syncthreads();
    #pragma unroll
    for (int kk = 0; kk < 32; ++kk) {
      float mm[4], nn[4];
      #pragma unroll
      for (int q = 0; q < 4; ++q) mm[q] = sA[kk][tm * 4 + q];
      #pragma unroll
      for (int q = 0; q < 4; ++q) nn[q] = sW[kk][tn * 4 + q];
      #pragma unroll
      for (int r = 0; r < 4; ++r)
        #pragma unroll
        for (int c = 0; c < 4; ++c)
          acc[r][c] = fmaf(mm[r], nn[c], acc[r][c]);
    }
    __syncthreads();
  }
  #pragma unroll
  for (int r = 0; r < 4; ++r) {
    int bb = b0 + tm * 4 + r;
    float4 v = make_float4(acc[r][0] + bias[o0 + tn * 4 + 0],
                           acc[r][1] + bias[o0 + tn * 4 + 1],
                           acc[r][2] + bias[o0 + tn * 4 + 2],
                           acc[r][3] + bias[o0 + tn * 4 + 3]);
    *(float4*)&y[bb * 128 + o0 + tn * 4] = v;
  }
}

extern "C" void kernel_launch(void* const* d_in, const int* in_sizes, int n_in,
                              void* d_out, int out_size, void* d_ws, size_t ws_size,
                              hipStream_t stream) {
  const float* u   = (const float*)d_in[0];
  const float* X   = (const float*)d_in[1];
  const float* Y   = (const float*)d_in[2];
  const float* B2  = (const float*)d_in[3];
  const float* C2  = (const float*)d_in[4];
  const float* D21 = (const float*)d_in[5];
  const float* D22 = (const float*)d_in[6];
  const float* D12 = (const float*)d_in[7];
  const float* x0  = (const float*)d_in[8];

  float* ws = (float*)d_ws;
  float* H     = ws;                    // 1327104
  float* M     = H + 1327104;           // 512*640 = 327680
  float* Gt    = M + 327680;            // 65536
  float* W1    = Gt + 65536;            // 16384
  float* W2    = W1 + 16384;            // 16384
  float* D11   = W2 + 16384;            // 16384
  float* Lam   = D11 + 16384;           // 128
  float* xc    = Lam + 128;             // 128
  float* Fx    = xc + 128;              // 512
  float* bias  = Fx + 512;              // 128
  float* baseT = bias + 128 + 64;       // 128*16384 = 2097152
  float* wT    = baseT;                 // in-place
  // Dfac / invUg alias the dead H11 region (H rows 0..511 cols 0..511 are only read by
  // k_assemble, stream-ordered before the LU). 2 * 8 * 64*64 = 65536 floats = ~57 H-rows.
  float* Dfac  = H;
  float* invUg = H + 32768;
  float* y     = (float*)d_out;

  k_xtx<<<dim3(18, 18), 256, 0, stream>>>(X, H);
  k_assemble<<<388, 256, 0, stream>>>(H, Y, C2, x0, M, D11, Lam, xc, Fx);

  for (int kb = 0; kb < 8; ++kb) {
    k_lu_dp<<<16 - 2 * kb, 64, 0, stream>>>(M, Dfac, kb);
    if (kb < 7)
      k_lu_trailing<<<dim3(9 - kb, 7 - kb), 256, 0, stream>>>(M, kb);
  }

  k_inv<<<8, 64, 0, stream>>>(Dfac, invUg);
  k_bs<<<8, 512, 0, stream>>>(M, invUg, Gt);
  k_wass<<<129, 256, 0, stream>>>(Gt, H, B2, D21, D22, Fx, W1, W2, bias);

  k_ud<<<dim3(256, 2), 256, 0, stream>>>(u, D12, xc, baseT);
  k_scan<<<256, 64, 0, stream>>>(baseT, D11, Lam, wT);
  k_y<<<dim3(256, 2), 256, 0, stream>>>(wT, u, W1, W2, bias, y);
}

// Round 7
// 991.587 us; speedup vs baseline: 1.9875x; 1.1448x over previous
//
#include <hip/hip_runtime.h>
#include <math.h>

#define EPS_C 0.001f
#define BATCH 16384

// ---------------- H = X^T X + eps*I  (1152x1152), symmetric: compute bi<=bj, mirror ----------------
__global__ __launch_bounds__(256) void k_xtx(const float* __restrict__ X, float* __restrict__ H) {
  __shared__ float smem[64 * 65];
  const int bi64 = blockIdx.x, bj64 = blockIdx.y;
  if (bi64 > bj64) return;
  float (*sA)[65] = (float(*)[65])smem;
  float (*sB)[65] = (float(*)[65])(smem + 32 * 65);
  const int t = threadIdx.x;
  const int bi = bi64 * 64, bj = bj64 * 64;
  const int tj = t & 15, ti = t >> 4;
  float acc[4][4] = {};
  for (int k0 = 0; k0 < 1152; k0 += 32) {
    #pragma unroll
    for (int l = 0; l < 2; ++l) {
      int idx = t + l * 256;
      int kk = idx >> 4, c4 = (idx & 15) << 2;
      float4 va = *(const float4*)&X[(k0 + kk) * 1152 + bi + c4];
      sA[kk][c4 + 0] = va.x; sA[kk][c4 + 1] = va.y; sA[kk][c4 + 2] = va.z; sA[kk][c4 + 3] = va.w;
      float4 vb = *(const float4*)&X[(k0 + kk) * 1152 + bj + c4];
      sB[kk][c4 + 0] = vb.x; sB[kk][c4 + 1] = vb.y; sB[kk][c4 + 2] = vb.z; sB[kk][c4 + 3] = vb.w;
    }
    __syncthreads();
    #pragma unroll
    for (int kk = 0; kk < 32; ++kk) {
      float am[4], bn[4];
      #pragma unroll
      for (int q = 0; q < 4; ++q) am[q] = sA[kk][ti * 4 + q];
      #pragma unroll
      for (int q = 0; q < 4; ++q) bn[q] = sB[kk][tj * 4 + q];
      #pragma unroll
      for (int r = 0; r < 4; ++r)
        #pragma unroll
        for (int c = 0; c < 4; ++c)
          acc[r][c] = fmaf(am[r], bn[c], acc[r][c]);
    }
    __syncthreads();
  }
  #pragma unroll
  for (int r = 0; r < 4; ++r) {
    int gi = bi + ti * 4 + r;
    float vv[4];
    #pragma unroll
    for (int c = 0; c < 4; ++c) {
      vv[c] = acc[r][c];
      if (gi == bj + tj * 4 + c) vv[c] += EPS_C;
    }
    float4 o = make_float4(vv[0], vv[1], vv[2], vv[3]);
    *(float4*)&H[gi * 1152 + bj + tj * 4] = o;
  }
  if (bi64 < bj64) {
    float (*tr)[65] = (float(*)[65])smem;
    #pragma unroll
    for (int r = 0; r < 4; ++r)
      #pragma unroll
      for (int c = 0; c < 4; ++c)
        tr[tj * 4 + c][ti * 4 + r] = acc[r][c];
    __syncthreads();
    #pragma unroll
    for (int l = 0; l < 4; ++l) {
      int e = t + l * 256;
      int row = e >> 4, c4 = (e & 15) << 2;
      float4 o = make_float4(tr[row][c4], tr[row][c4 + 1], tr[row][c4 + 2], tr[row][c4 + 3]);
      *(float4*)&H[(bj + row) * 1152 + bi + c4] = o;
    }
  }
}

// ---------------- assemble M=[E^T | C2^T], D11, Lam, xc, Fx ----------------
__global__ __launch_bounds__(256) void k_assemble(const float* __restrict__ H, const float* __restrict__ Y,
                           const float* __restrict__ C2, const float* __restrict__ x0,
                           float* __restrict__ M, float* __restrict__ D11,
                           float* __restrict__ Lam, float* __restrict__ xc, float* __restrict__ Fx) {
  const int b = blockIdx.x;
  const int t = threadIdx.x;
  if (b < 256) {
    __shared__ float tA[32][33], tB[32][33], tC[32][33];
    const int R0 = (b & 15) * 32, C0 = (b >> 4) * 32;
    const int c = t & 31, rr = t >> 5;
    #pragma unroll
    for (int p = 0; p < 4; ++p) {
      int row = rr + p * 8;
      tA[row][c] = H[(C0 + row) * 1152 + R0 + c];
      tB[row][c] = H[(640 + C0 + row) * 1152 + 640 + R0 + c];
      tC[row][c] = Y[(C0 + row) * 512 + R0 + c];
    }
    __syncthreads();
    #pragma unroll
    for (int p = 0; p < 4; ++p) {
      int r = rr + p * 8;
      float val = 0.5f * (tA[c][r] + tB[c][r] + tC[c][r] - Y[(R0 + r) * 512 + C0 + c]);
      M[(R0 + r) * 640 + C0 + c] = val;
    }
  } else if (b < 320) {
    int e0 = (b - 256) * 1024;
    #pragma unroll
    for (int l = 0; l < 4; ++l) {
      int e = e0 + l * 256 + t;
      int r = e >> 7, o = e & 127;
      M[r * 640 + 512 + o] = C2[o * 512 + r];
    }
  } else if (b < 384) {
    int e = (b - 320) * 256 + t;
    int i = e >> 7, j = e & 127;
    D11[e] = (j < i) ? -H[(512 + i) * 1152 + 512 + j] : 0.0f;
  } else if (b == 384) {
    if (t < 128) Lam[t] = 0.5f * H[(512 + t) * 1152 + 512 + t];
  } else if (b == 385) {
    if (t < 128) {
      float s = 0.f;
      for (int a = 0; a < 512; ++a) s = fmaf(H[(512 + t) * 1152 + a], x0[a], s);
      xc[t] = -s;
    }
  } else {
    int r = (b - 386) * 256 + t;
    float s = 0.f;
    for (int a = 0; a < 512; ++a) s = fmaf(H[(640 + r) * 1152 + a], x0[a], s);
    Fx[r] = s;
  }
}

// ---------------- fused diag+panels: every block redundantly factors the 64x64 diag in registers
//                  (no inter-block sync); block 0 persists factored diag to Dfac (NOT in-place: race-free) ----------------
__global__ __launch_bounds__(64) void k_lu_dp(float* __restrict__ M, float* __restrict__ Dfac, int kb) {
  __shared__ float sD[64 * 65];
  __shared__ float sRD[64];
  const int t = threadIdx.x;
  const int nU = 9 - kb;
  const int pb = blockIdx.x;
  // issue panel loads early (panel strips are untouched by the diag factor)
  float v[64];
  int c = 0, rr = 0;
  if (pb < nU) {
    c = 64 * (kb + 1) + pb * 64 + t;
    #pragma unroll
    for (int i = 0; i < 64; ++i) v[i] = M[(kb * 64 + i) * 640 + c];
  } else {
    rr = 64 * (kb + 1) + (pb - nU) * 64 + t;
    #pragma unroll
    for (int i = 0; i < 16; ++i) *(float4*)&v[i * 4] = *(const float4*)&M[rr * 640 + kb * 64 + i * 4];
  }
  // redundant in-register LU factor of diag (reads ORIGINAL M diag; M's diag is never overwritten)
  {
    const float* blk = M + kb * 64 * 640 + kb * 64;
    float col[64];
    #pragma unroll
    for (int r = 0; r < 64; ++r) col[r] = blk[r * 640 + t];
    float invp = 1.0f;
    #pragma unroll
    for (int k = 0; k < 64; ++k) {
      float piv = __shfl(col[k], k);
      float inv = 1.0f / piv;
      if (t == k) invp = inv;
      float m = col[k] * inv;
      bool act = t > k;
      #pragma unroll
      for (int r = k + 1; r < 64; ++r) {
        float ckr = __shfl(col[r], k);
        if (act) col[r] -= ckr * m;
      }
    }
    #pragma unroll
    for (int r = 0; r < 64; ++r) {
      if (r > t) col[r] *= invp;
      sD[r * 65 + t] = col[r];
      if (pb == 0) Dfac[kb * 4096 + r * 64 + t] = col[r];
    }
    sRD[t] = invp;  // == 1/sD[t*65+t] bitwise
  }
  __syncthreads();
  if (pb < nU) {
    #pragma unroll
    for (int i = 1; i < 64; ++i) {
      float a0 = v[i], a1 = 0.f;
      #pragma unroll
      for (int j = 0; j < i; j += 2) {
        a0 = fmaf(-sD[i * 65 + j], v[j], a0);
        if (j + 1 < i) a1 = fmaf(-sD[i * 65 + j + 1], v[j + 1], a1);
      }
      v[i] = a0 + a1;
    }
    #pragma unroll
    for (int i = 0; i < 64; ++i) M[(kb * 64 + i) * 640 + c] = v[i];
  } else {
    #pragma unroll
    for (int j = 0; j < 64; ++j) {
      float a0 = v[j], a1 = 0.f;
      #pragma unroll
      for (int i = 0; i < j; i += 2) {
        a0 = fmaf(-v[i], sD[i * 65 + j], a0);
        if (i + 1 < j) a1 = fmaf(-v[i + 1], sD[(i + 1) * 65 + j], a1);
      }
      v[j] = (a0 + a1) * sRD[j];
    }
    #pragma unroll
    for (int i = 0; i < 16; ++i) *(float4*)&M[rr * 640 + kb * 64 + i * 4] = *(float4*)&v[i * 4];
  }
}

// ---------------- trailing update: A22 -= L21 * U12 (cols include augmented) ----------------
__global__ __launch_bounds__(256) void k_lu_trailing(float* __restrict__ M, int kb) {
  __shared__ float sL[32][65];
  __shared__ float sU[32][65];
  const int t = threadIdx.x;
  const int base = 64 * (kb + 1);
  const int r0 = base + blockIdx.y * 64, c0 = base + blockIdx.x * 64;
  const int tj = t & 15, ti = t >> 4;
  float acc[4][4] = {};
  for (int k0 = 0; k0 < 64; k0 += 32) {
    #pragma unroll
    for (int l = 0; l < 2; ++l) {
      int idx = t + l * 256;
      int row = idx >> 3, k4 = (idx & 7) << 2;
      float4 v = *(const float4*)&M[(r0 + row) * 640 + kb * 64 + k0 + k4];
      sL[k4 + 0][row] = v.x; sL[k4 + 1][row] = v.y; sL[k4 + 2][row] = v.z; sL[k4 + 3][row] = v.w;
      int kk = idx >> 4, c4 = (idx & 15) << 2;
      float4 u4 = *(const float4*)&M[(kb * 64 + k0 + kk) * 640 + c0 + c4];
      sU[kk][c4 + 0] = u4.x; sU[kk][c4 + 1] = u4.y; sU[kk][c4 + 2] = u4.z; sU[kk][c4 + 3] = u4.w;
    }
    __syncthreads();
    #pragma unroll
    for (int kk = 0; kk < 32; ++kk) {
      float am[4], bn[4];
      #pragma unroll
      for (int q = 0; q < 4; ++q) am[q] = sL[kk][ti * 4 + q];
      #pragma unroll
      for (int q = 0; q < 4; ++q) bn[q] = sU[kk][tj * 4 + q];
      #pragma unroll
      for (int r = 0; r < 4; ++r)
        #pragma unroll
        for (int c = 0; c < 4; ++c)
          acc[r][c] = fmaf(am[r], bn[c], acc[r][c]);
    }
    __syncthreads();
  }
  #pragma unroll
  for (int r = 0; r < 4; ++r) {
    float4 old = *(float4*)&M[(r0 + ti * 4 + r) * 640 + c0 + tj * 4];
    old.x -= acc[r][0]; old.y -= acc[r][1]; old.z -= acc[r][2]; old.w -= acc[r][3];
    *(float4*)&M[(r0 + ti * 4 + r) * 640 + c0 + tj * 4] = old;
  }
}

// ---------------- invert each factored 64x64 diag block: invU[kb] = U_kk^-1 (8 parallel blocks) ----------------
__global__ __launch_bounds__(64) void k_inv(const float* __restrict__ Dfac, float* __restrict__ invU) {
  __shared__ float sD[64 * 65];
  __shared__ float srs[64];
  const int t = threadIdx.x;
  const int kb = blockIdx.x;
  for (int l = 0; l < 64; ++l) sD[l * 65 + t] = Dfac[kb * 4096 + l * 64 + t];
  __syncthreads();
  srs[t] = 1.0f / sD[t * 65 + t];
  __syncthreads();
  // column t of U^-1 via back-substitution, fully unrolled, registers only
  float v[64];
  #pragma unroll
  for (int i = 0; i < 64; ++i) v[i] = (i == t) ? srs[t] : 0.0f;
  #pragma unroll
  for (int i = 62; i >= 0; --i) {
    float a0 = 0.f, a1 = 0.f;
    #pragma unroll
    for (int j = i + 1; j < 64; j += 2) {
      a0 = fmaf(-sD[i * 65 + j], v[j], a0);
      if (j + 1 < 64) a1 = fmaf(-sD[i * 65 + j + 1], v[j + 1], a1);
    }
    float nv = (a0 + a1) * srs[i];
    v[i] = (i == t) ? v[i] : nv;   // nv==0 naturally for i>t (strictly-upper zeros)
  }
  #pragma unroll
  for (int i = 0; i < 64; ++i) invU[kb * 4096 + i * 64 + t] = v[i];
}

// ---------------- backward solve U * Gt = Z : 8 INDEPENDENT column-slice blocks (16 cols each).
//                  Z slice lives in LDS; diag solves are invU GEMMs; right-looking updates.
//                  All per-thread arrays statically indexed (FULL unrolls) -- no scratch spill. ----------------
__global__ __launch_bounds__(512) void k_bs(const float* __restrict__ M, const float* __restrict__ invUg,
                                            float* __restrict__ Gt) {
  __shared__ float sZ[512 * 17];     // 512 rows x 16 cols, stride 17 (bank-spread)
  __shared__ float sU[64 * 65];
  __shared__ float sI[64 * 64];
  const int t = threadIdx.x;
  const int c0 = blockIdx.x * 16;
  const int o = t & 15, q = t >> 4;  // q in [0,32): row-thread groups
  // load this block's Z slice (augmented columns of M)
  #pragma unroll
  for (int l = 0; l < 16; ++l) {
    int e = t + l * 512;
    int r = e >> 4, oo = e & 15;
    sZ[r * 17 + oo] = M[r * 640 + 512 + c0 + oo];
  }
  for (int kb = 7; kb >= 0; --kb) {
    // stage invU(kb)
    #pragma unroll
    for (int l = 0; l < 8; ++l) {
      int e = t + l * 512;
      sI[e] = invUg[kb * 4096 + e];
    }
    __syncthreads();   // covers initial sZ load (first iter) + sI staging + prior updates
    // x_kb = invU @ z_kb : read phase (same even/odd a0/a1 chain as round-5's validated GEMM)
    float xv[2];
    #pragma unroll
    for (int rr = 0; rr < 2; ++rr) {
      int i = q * 2 + rr;
      float a0 = 0.f, a1 = 0.f;
      #pragma unroll
      for (int k = 0; k < 64; k += 2) {
        a0 = fmaf(sI[i * 64 + k], sZ[(kb * 64 + k) * 17 + o], a0);
        a1 = fmaf(sI[i * 64 + k + 1], sZ[(kb * 64 + k + 1) * 17 + o], a1);
      }
      xv[rr] = a0 + a1;
    }
    __syncthreads();   // all reads of z_kb done before overwrite
    #pragma unroll
    for (int rr = 0; rr < 2; ++rr) {
      int i = q * 2 + rr;
      sZ[(kb * 64 + i) * 17 + o] = xv[rr];
      Gt[(kb * 64 + i) * 128 + c0 + o] = xv[rr];
    }
    __syncthreads();
    if (kb == 0) break;
    // hoist x_kb into registers once (each thread: its own column o) -- STATIC indices only
    float xk[64];
    #pragma unroll
    for (int k = 0; k < 64; ++k) xk[k] = sZ[(kb * 64 + k) * 17 + o];
    // updates: z_i -= U(i,kb) @ x_kb for i < kb (same per-element sequential fmaf chain as before)
    for (int i = 0; i < kb; ++i) {
      #pragma unroll
      for (int l = 0; l < 8; ++l) {
        int e = t + l * 512;
        int r = e >> 6, k = e & 63;
        sU[r * 65 + k] = M[(i * 64 + r) * 640 + kb * 64 + k];
      }
      __syncthreads();
      #pragma unroll
      for (int rr = 0; rr < 2; ++rr) {
        int row = q * 2 + rr;
        float acc = sZ[(i * 64 + row) * 17 + o];
        #pragma unroll
        for (int k = 0; k < 64; ++k)
          acc = fmaf(-sU[row * 65 + k], xk[k], acc);
        sZ[(i * 64 + row) * 17 + o] = acc;
      }
      __syncthreads();
    }
  }
}

// ---------------- W1 = G@B1 + D21, W2 = G@B2 + D22, bias = G@Fx ----------------
__global__ void k_wass(const float* __restrict__ Gt, const float* __restrict__ H,
                       const float* __restrict__ B2, const float* __restrict__ D21,
                       const float* __restrict__ D22, const float* __restrict__ Fx,
                       float* __restrict__ W1, float* __restrict__ W2, float* __restrict__ bias) {
  int idx = blockIdx.x * 256 + threadIdx.x;
  if (idx < 16384) {
    int o = idx >> 7, j = idx & 127;
    float s = 0.f;
    for (int a = 0; a < 512; ++a) s = fmaf(Gt[a * 128 + o], H[(640 + a) * 1152 + 512 + j], s);
    W1[idx] = s + D21[idx];
  } else if (idx < 32768) {
    int q = idx - 16384;
    int o = q >> 7, j = q & 127;
    float s = 0.f;
    for (int a = 0; a < 512; ++a) s = fmaf(Gt[a * 128 + o], B2[a * 128 + j], s);
    W2[q] = s + D22[q];
  } else if (idx < 32768 + 128) {
    int o = idx - 32768;
    float s = 0.f;
    for (int a = 0; a < 512; ++a) s = fmaf(Gt[a * 128 + o], Fx[a], s);
    bias[o] = s;
  }
}

// ---------------- baseT[i][b] = xc[i] + (u @ D12^T)[b][i] ----------------
__global__ __launch_bounds__(256) void k_ud(const float* __restrict__ u, const float* __restrict__ D12,
                                            const float* __restrict__ xc, float* __restrict__ baseT) {
  __shared__ float sU[32][65];
  __shared__ float sD[32][65];
  const int t = threadIdx.x;
  const int b0 = blockIdx.x * 64, i0 = blockIdx.y * 64;
  const int tm = t & 15, tn = t >> 4;
  float acc[4][4] = {};
  for (int k0 = 0; k0 < 128; k0 += 32) {
    #pragma unroll
    for (int l = 0; l < 2; ++l) {
      int idx = t + l * 256;
      int row = idx >> 3, k4 = (idx & 7) << 2;
      float4 v = *(const float4*)&u[(b0 + row) * 128 + k0 + k4];
      sU[k4 + 0][row] = v.x; sU[k4 + 1][row] = v.y; sU[k4 + 2][row] = v.z; sU[k4 + 3][row] = v.w;
      float4 d = *(const float4*)&D12[(i0 + row) * 128 + k0 + k4];
      sD[k4 + 0][row] = d.x; sD[k4 + 1][row] = d.y; sD[k4 + 2][row] = d.z; sD[k4 + 3][row] = d.w;
    }
    __syncthreads();
    #pragma unroll
    for (int kk = 0; kk < 32; ++kk) {
      float mm[4], nn[4];
      #pragma unroll
      for (int q = 0; q < 4; ++q) mm[q] = sU[kk][tm * 4 + q];
      #pragma unroll
      for (int q = 0; q < 4; ++q) nn[q] = sD[kk][tn * 4 + q];
      #pragma unroll
      for (int c = 0; c < 4; ++c)
        #pragma unroll
        for (int r = 0; r < 4; ++r)
          acc[c][r] = fmaf(nn[c], mm[r], acc[c][r]);
    }
    __syncthreads();
  }
  #pragma unroll
  for (int c = 0; c < 4; ++c) {
    int i = i0 + tn * 4 + c;
    float xcv = xc[i];
    float4 v = make_float4(acc[c][0] + xcv, acc[c][1] + xcv, acc[c][2] + xcv, acc[c][3] + xcv);
    *(float4*)&baseT[i * BATCH + b0 + tm * 4] = v;
  }
}

// ---------------- scan: w[i] = tanh((base_i + sum_{j<i} D11[i][j] w[j]) / Lam[i]) ----------------
__global__ __launch_bounds__(64) void k_scan(const float* __restrict__ baseT, const float* __restrict__ D11g,
                                             const float* __restrict__ Lam, float* __restrict__ wT) {
  const int b = blockIdx.x * 64 + threadIdx.x;
  float w[128];
  #pragma unroll
  for (int i = 0; i < 128; ++i) {
    float acc0 = baseT[i * BATCH + b], acc1 = 0.f, acc2 = 0.f, acc3 = 0.f;
    const float* __restrict__ Drow = D11g + i * 128;
    #pragma unroll
    for (int j = 0; j + 4 <= i; j += 4) {
      acc0 = fmaf(w[j + 0], Drow[j + 0], acc0);
      acc1 = fmaf(w[j + 1], Drow[j + 1], acc1);
      acc2 = fmaf(w[j + 2], Drow[j + 2], acc2);
      acc3 = fmaf(w[j + 3], Drow[j + 3], acc3);
    }
    #pragma unroll
    for (int j = i & ~3; j < i; ++j) acc0 = fmaf(w[j], Drow[j], acc0);
    float zv = ((acc0 + acc1) + (acc2 + acc3)) / Lam[i];
    float az = fabsf(zv);
    float e = __expf(-2.0f * az);
    float th = (1.0f - e) / (1.0f + e);
    w[i] = copysignf(th, zv);
    wT[i * BATCH + b] = w[i];
  }
}

// ---------------- y = w@W1^T + u@W2^T + bias ----------------
__global__ __launch_bounds__(256) void k_y(const float* __restrict__ wT, const float* __restrict__ u,
                                           const float* __restrict__ W1, const float* __restrict__ W2,
                                           const float* __restrict__ bias, float* __restrict__ y) {
  __shared__ float sA[32][65];
  __shared__ float sW[32][65];
  const int t = threadIdx.x;
  const int b0 = blockIdx.x * 64, o0 = blockIdx.y * 64;
  const int tn = t & 15, tm = t >> 4;
  float acc[4][4] = {};
  for (int k0 = 0; k0 < 128; k0 += 32) {
    #pragma unroll
    for (int l = 0; l < 2; ++l) {
      int idx = t + l * 256;
      int kk = idx >> 4, c4 = (idx & 15) << 2;
      float4 v = *(const float4*)&wT[(k0 + kk) * BATCH + b0 + c4];
      sA[kk][c4 + 0] = v.x; sA[kk][c4 + 1] = v.y; sA[kk][c4 + 2] = v.z; sA[kk][c4 + 3] = v.w;
      int row = idx >> 3, k4 = (idx & 7) << 2;
      float4 d = *(const float4*)&W1[(o0 + row) * 128 + k0 + k4];
      sW[k4 + 0][row] = d.x; sW[k4 + 1][row] = d.y; sW[k4 + 2][row] = d.z; sW[k4 + 3][row] = d.w;
    }
    __syncthreads();
    #pragma unroll
    for (int kk = 0; kk < 32; ++kk) {
      float mm[4], nn[4];
      #pragma unroll
      for (int q = 0; q < 4; ++q) mm[q] = sA[kk][tm * 4 + q];
      #pragma unroll
      for (int q = 0; q < 4; ++q) nn[q] = sW[kk][tn * 4 + q];
      #pragma unroll
      for (int r = 0; r < 4; ++r)
        #pragma unroll
        for (int c = 0; c < 4; ++c)
          acc[r][c] = fmaf(mm[r], nn[c], acc[r][c]);
    }
    __syncthreads();
  }
  for (int k0 = 0; k0 < 128; k0 += 32) {
    #pragma unroll
    for (int l = 0; l < 2; ++l) {
      int idx = t + l * 256;
      int row = idx >> 3, k4 = (idx & 7) << 2;
      float4 v = *(const float4*)&u[(b0 + row) * 128 + k0 + k4];
      sA[k4 + 0][row] = v.x; sA[k4 + 1][row] = v.y; sA[k4 + 2][row] = v.z; sA[k4 + 3][row] = v.w;
      float4 d = *(const float4*)&W2[(o0 + row) * 128 + k0 + k4];
      sW[k4 + 0][row] = d.x; sW[k4 + 1][row] = d.y; sW[k4 + 2][row] = d.z; sW[k4 + 3][row] = d.w;
    }
    __syncthreads();
    #pragma unroll
    for (int kk = 0; kk < 32; ++kk) {
      float mm[4], nn[4];
      #pragma unroll
      for (int q = 0; q < 4; ++q) mm[q] = sA[kk][tm * 4 + q];
      #pragma unroll
      for (int q = 0; q < 4; ++q) nn[q] = sW[kk][tn * 4 + q];
      #pragma unroll
      for (int r = 0; r < 4; ++r)
        #pragma unroll
        for (int c = 0; c < 4; ++c)
          acc[r][c] = fmaf(mm[r], nn[c], acc[r][c]);
    }
    __syncthreads();
  }
  #pragma unroll
  for (int r = 0; r < 4; ++r) {
    int bb = b0 + tm * 4 + r;
    float4 v = make_float4(acc[r][0] + bias[o0 + tn * 4 + 0],
                           acc[r][1] + bias[o0 + tn * 4 + 1],
                           acc[r][2] + bias[o0 + tn * 4 + 2],
                           acc[r][3] + bias[o0 + tn * 4 + 3]);
    *(float4*)&y[bb * 128 + o0 + tn * 4] = v;
  }
}

extern "C" void kernel_launch(void* const* d_in, const int* in_sizes, int n_in,
                              void* d_out, int out_size, void* d_ws, size_t ws_size,
                              hipStream_t stream) {
  const float* u   = (const float*)d_in[0];
  const float* X   = (const float*)d_in[1];
  const float* Y   = (const float*)d_in[2];
  const float* B2  = (const float*)d_in[3];
  const float* C2  = (const float*)d_in[4];
  const float* D21 = (const float*)d_in[5];
  const float* D22 = (const float*)d_in[6];
  const float* D12 = (const float*)d_in[7];
  const float* x0  = (const float*)d_in[8];

  float* ws = (float*)d_ws;
  float* H     = ws;                    // 1327104
  float* M     = H + 1327104;           // 512*640 = 327680
  float* Gt    = M + 327680;            // 65536
  float* W1    = Gt + 65536;            // 16384
  float* W2    = W1 + 16384;            // 16384
  float* D11   = W2 + 16384;            // 16384
  float* Lam   = D11 + 16384;           // 128
  float* xc    = Lam + 128;             // 128
  float* Fx    = xc + 128;              // 512
  float* bias  = Fx + 512;              // 128
  float* baseT = bias + 128 + 64;       // 128*16384 = 2097152
  float* wT    = baseT;                 // in-place
  // Dfac / invUg alias the dead H11 region (H rows 0..511 cols 0..511 are only read by
  // k_assemble, stream-ordered before the LU). 2 * 8 * 64*64 = 65536 floats = ~57 H-rows.
  float* Dfac  = H;
  float* invUg = H + 32768;
  float* y     = (float*)d_out;

  k_xtx<<<dim3(18, 18), 256, 0, stream>>>(X, H);
  k_assemble<<<388, 256, 0, stream>>>(H, Y, C2, x0, M, D11, Lam, xc, Fx);

  for (int kb = 0; kb < 8; ++kb) {
    k_lu_dp<<<16 - 2 * kb, 64, 0, stream>>>(M, Dfac, kb);
    if (kb < 7)
      k_lu_trailing<<<dim3(9 - kb, 7 - kb), 256, 0, stream>>>(M, kb);
  }

  k_inv<<<8, 64, 0, stream>>>(Dfac, invUg);
  k_bs<<<8, 512, 0, stream>>>(M, invUg, Gt);
  k_wass<<<129, 256, 0, stream>>>(Gt, H, B2, D21, D22, Fx, W1, W2, bias);

  k_ud<<<dim3(256, 2), 256, 0, stream>>>(u, D12, xc, baseT);
  k_scan<<<256, 64, 0, stream>>>(baseT, D11, Lam, wT);
  k_y<<<dim3(256, 2), 256, 0, stream>>>(wT, u, W1, W2, bias, y);
}

// Round 8
// 966.191 us; speedup vs baseline: 2.0398x; 1.0263x over previous
//
#include <hip/hip_runtime.h>
#include <math.h>

#define EPS_C 0.001f
#define BATCH 16384

// ---------------- H = X^T X + eps*I  (1152x1152), symmetric: compute bi<=bj, mirror ----------------
__global__ __launch_bounds__(256) void k_xtx(const float* __restrict__ X, float* __restrict__ H) {
  __shared__ float smem[64 * 65];
  const int bi64 = blockIdx.x, bj64 = blockIdx.y;
  if (bi64 > bj64) return;
  float (*sA)[65] = (float(*)[65])smem;
  float (*sB)[65] = (float(*)[65])(smem + 32 * 65);
  const int t = threadIdx.x;
  const int bi = bi64 * 64, bj = bj64 * 64;
  const int tj = t & 15, ti = t >> 4;
  float acc[4][4] = {};
  for (int k0 = 0; k0 < 1152; k0 += 32) {
    #pragma unroll
    for (int l = 0; l < 2; ++l) {
      int idx = t + l * 256;
      int kk = idx >> 4, c4 = (idx & 15) << 2;
      float4 va = *(const float4*)&X[(k0 + kk) * 1152 + bi + c4];
      sA[kk][c4 + 0] = va.x; sA[kk][c4 + 1] = va.y; sA[kk][c4 + 2] = va.z; sA[kk][c4 + 3] = va.w;
      float4 vb = *(const float4*)&X[(k0 + kk) * 1152 + bj + c4];
      sB[kk][c4 + 0] = vb.x; sB[kk][c4 + 1] = vb.y; sB[kk][c4 + 2] = vb.z; sB[kk][c4 + 3] = vb.w;
    }
    __syncthreads();
    #pragma unroll
    for (int kk = 0; kk < 32; ++kk) {
      float am[4], bn[4];
      #pragma unroll
      for (int q = 0; q < 4; ++q) am[q] = sA[kk][ti * 4 + q];
      #pragma unroll
      for (int q = 0; q < 4; ++q) bn[q] = sB[kk][tj * 4 + q];
      #pragma unroll
      for (int r = 0; r < 4; ++r)
        #pragma unroll
        for (int c = 0; c < 4; ++c)
          acc[r][c] = fmaf(am[r], bn[c], acc[r][c]);
    }
    __syncthreads();
  }
  #pragma unroll
  for (int r = 0; r < 4; ++r) {
    int gi = bi + ti * 4 + r;
    float vv[4];
    #pragma unroll
    for (int c = 0; c < 4; ++c) {
      vv[c] = acc[r][c];
      if (gi == bj + tj * 4 + c) vv[c] += EPS_C;
    }
    float4 o = make_float4(vv[0], vv[1], vv[2], vv[3]);
    *(float4*)&H[gi * 1152 + bj + tj * 4] = o;
  }
  if (bi64 < bj64) {
    float (*tr)[65] = (float(*)[65])smem;
    #pragma unroll
    for (int r = 0; r < 4; ++r)
      #pragma unroll
      for (int c = 0; c < 4; ++c)
        tr[tj * 4 + c][ti * 4 + r] = acc[r][c];
    __syncthreads();
    #pragma unroll
    for (int l = 0; l < 4; ++l) {
      int e = t + l * 256;
      int row = e >> 4, c4 = (e & 15) << 2;
      float4 o = make_float4(tr[row][c4], tr[row][c4 + 1], tr[row][c4 + 2], tr[row][c4 + 3]);
      *(float4*)&H[(bj + row) * 1152 + bi + c4] = o;
    }
  }
}

// ---------------- assemble M=[E^T | C2^T], D11, Lam, xc, Fx ----------------
__global__ __launch_bounds__(256) void k_assemble(const float* __restrict__ H, const float* __restrict__ Y,
                           const float* __restrict__ C2, const float* __restrict__ x0,
                           float* __restrict__ M, float* __restrict__ D11,
                           float* __restrict__ Lam, float* __restrict__ xc, float* __restrict__ Fx) {
  const int b = blockIdx.x;
  const int t = threadIdx.x;
  if (b < 256) {
    __shared__ float tA[32][33], tB[32][33], tC[32][33];
    const int R0 = (b & 15) * 32, C0 = (b >> 4) * 32;
    const int c = t & 31, rr = t >> 5;
    #pragma unroll
    for (int p = 0; p < 4; ++p) {
      int row = rr + p * 8;
      tA[row][c] = H[(C0 + row) * 1152 + R0 + c];
      tB[row][c] = H[(640 + C0 + row) * 1152 + 640 + R0 + c];
      tC[row][c] = Y[(C0 + row) * 512 + R0 + c];
    }
    __syncthreads();
    #pragma unroll
    for (int p = 0; p < 4; ++p) {
      int r = rr + p * 8;
      float val = 0.5f * (tA[c][r] + tB[c][r] + tC[c][r] - Y[(R0 + r) * 512 + C0 + c]);
      M[(R0 + r) * 640 + C0 + c] = val;
    }
  } else if (b < 320) {
    int e0 = (b - 256) * 1024;
    #pragma unroll
    for (int l = 0; l < 4; ++l) {
      int e = e0 + l * 256 + t;
      int r = e >> 7, o = e & 127;
      M[r * 640 + 512 + o] = C2[o * 512 + r];
    }
  } else if (b < 384) {
    int e = (b - 320) * 256 + t;
    int i = e >> 7, j = e & 127;
    D11[e] = (j < i) ? -H[(512 + i) * 1152 + 512 + j] : 0.0f;
  } else if (b == 384) {
    if (t < 128) Lam[t] = 0.5f * H[(512 + t) * 1152 + 512 + t];
  } else if (b == 385) {
    if (t < 128) {
      float s = 0.f;
      for (int a = 0; a < 512; ++a) s = fmaf(H[(512 + t) * 1152 + a], x0[a], s);
      xc[t] = -s;
    }
  } else {
    int r = (b - 386) * 256 + t;
    float s = 0.f;
    for (int a = 0; a < 512; ++a) s = fmaf(H[(640 + r) * 1152 + a], x0[a], s);
    Fx[r] = s;
  }
}

// ---------------- fused diag+panels: every block redundantly factors the 64x64 diag in registers
//                  (no inter-block sync); block 0 persists factored diag to Dfac (NOT in-place: race-free) ----------------
__global__ __launch_bounds__(64) void k_lu_dp(float* __restrict__ M, float* __restrict__ Dfac, int kb) {
  __shared__ float sD[64 * 65];
  __shared__ float sRD[64];
  const int t = threadIdx.x;
  const int nU = 9 - kb;
  const int pb = blockIdx.x;
  // issue panel loads early (panel strips are untouched by the diag factor)
  float v[64];
  int c = 0, rr = 0;
  if (pb < nU) {
    c = 64 * (kb + 1) + pb * 64 + t;
    #pragma unroll
    for (int i = 0; i < 64; ++i) v[i] = M[(kb * 64 + i) * 640 + c];
  } else {
    rr = 64 * (kb + 1) + (pb - nU) * 64 + t;
    #pragma unroll
    for (int i = 0; i < 16; ++i) *(float4*)&v[i * 4] = *(const float4*)&M[rr * 640 + kb * 64 + i * 4];
  }
  // redundant in-register LU factor of diag (reads ORIGINAL M diag; M's diag is never overwritten)
  {
    const float* blk = M + kb * 64 * 640 + kb * 64;
    float col[64];
    #pragma unroll
    for (int r = 0; r < 64; ++r) col[r] = blk[r * 640 + t];
    float invp = 1.0f;
    #pragma unroll
    for (int k = 0; k < 64; ++k) {
      float piv = __shfl(col[k], k);
      float inv = 1.0f / piv;
      if (t == k) invp = inv;
      float m = col[k] * inv;
      bool act = t > k;
      #pragma unroll
      for (int r = k + 1; r < 64; ++r) {
        float ckr = __shfl(col[r], k);
        if (act) col[r] -= ckr * m;
      }
    }
    #pragma unroll
    for (int r = 0; r < 64; ++r) {
      if (r > t) col[r] *= invp;
      sD[r * 65 + t] = col[r];
      if (pb == 0) Dfac[kb * 4096 + r * 64 + t] = col[r];
    }
    sRD[t] = invp;  // == 1/sD[t*65+t] bitwise
  }
  __syncthreads();
  if (pb < nU) {
    #pragma unroll
    for (int i = 1; i < 64; ++i) {
      float a0 = v[i], a1 = 0.f;
      #pragma unroll
      for (int j = 0; j < i; j += 2) {
        a0 = fmaf(-sD[i * 65 + j], v[j], a0);
        if (j + 1 < i) a1 = fmaf(-sD[i * 65 + j + 1], v[j + 1], a1);
      }
      v[i] = a0 + a1;
    }
    #pragma unroll
    for (int i = 0; i < 64; ++i) M[(kb * 64 + i) * 640 + c] = v[i];
  } else {
    #pragma unroll
    for (int j = 0; j < 64; ++j) {
      float a0 = v[j], a1 = 0.f;
      #pragma unroll
      for (int i = 0; i < j; i += 2) {
        a0 = fmaf(-v[i], sD[i * 65 + j], a0);
        if (i + 1 < j) a1 = fmaf(-v[i + 1], sD[(i + 1) * 65 + j], a1);
      }
      v[j] = (a0 + a1) * sRD[j];
    }
    #pragma unroll
    for (int i = 0; i < 16; ++i) *(float4*)&M[rr * 640 + kb * 64 + i * 4] = *(float4*)&v[i * 4];
  }
}

// ---------------- trailing update: A22 -= L21 * U12 (cols include augmented) ----------------
__global__ __launch_bounds__(256) void k_lu_trailing(float* __restrict__ M, int kb) {
  __shared__ float sL[32][65];
  __shared__ float sU[32][65];
  const int t = threadIdx.x;
  const int base = 64 * (kb + 1);
  const int r0 = base + blockIdx.y * 64, c0 = base + blockIdx.x * 64;
  const int tj = t & 15, ti = t >> 4;
  float acc[4][4] = {};
  for (int k0 = 0; k0 < 64; k0 += 32) {
    #pragma unroll
    for (int l = 0; l < 2; ++l) {
      int idx = t + l * 256;
      int row = idx >> 3, k4 = (idx & 7) << 2;
      float4 v = *(const float4*)&M[(r0 + row) * 640 + kb * 64 + k0 + k4];
      sL[k4 + 0][row] = v.x; sL[k4 + 1][row] = v.y; sL[k4 + 2][row] = v.z; sL[k4 + 3][row] = v.w;
      int kk = idx >> 4, c4 = (idx & 15) << 2;
      float4 u4 = *(const float4*)&M[(kb * 64 + k0 + kk) * 640 + c0 + c4];
      sU[kk][c4 + 0] = u4.x; sU[kk][c4 + 1] = u4.y; sU[kk][c4 + 2] = u4.z; sU[kk][c4 + 3] = u4.w;
    }
    __syncthreads();
    #pragma unroll
    for (int kk = 0; kk < 32; ++kk) {
      float am[4], bn[4];
      #pragma unroll
      for (int q = 0; q < 4; ++q) am[q] = sL[kk][ti * 4 + q];
      #pragma unroll
      for (int q = 0; q < 4; ++q) bn[q] = sU[kk][tj * 4 + q];
      #pragma unroll
      for (int r = 0; r < 4; ++r)
        #pragma unroll
        for (int c = 0; c < 4; ++c)
          acc[r][c] = fmaf(am[r], bn[c], acc[r][c]);
    }
    __syncthreads();
  }
  #pragma unroll
  for (int r = 0; r < 4; ++r) {
    float4 old = *(float4*)&M[(r0 + ti * 4 + r) * 640 + c0 + tj * 4];
    old.x -= acc[r][0]; old.y -= acc[r][1]; old.z -= acc[r][2]; old.w -= acc[r][3];
    *(float4*)&M[(r0 + ti * 4 + r) * 640 + c0 + tj * 4] = old;
  }
}

// ---------------- invert each factored 64x64 diag block: invU[kb] = U_kk^-1 (8 parallel blocks) ----------------
__global__ __launch_bounds__(64) void k_inv(const float* __restrict__ Dfac, float* __restrict__ invU) {
  __shared__ float sD[64 * 65];
  __shared__ float srs[64];
  const int t = threadIdx.x;
  const int kb = blockIdx.x;
  for (int l = 0; l < 64; ++l) sD[l * 65 + t] = Dfac[kb * 4096 + l * 64 + t];
  __syncthreads();
  srs[t] = 1.0f / sD[t * 65 + t];
  __syncthreads();
  // column t of U^-1 via back-substitution, fully unrolled, registers only
  float v[64];
  #pragma unroll
  for (int i = 0; i < 64; ++i) v[i] = (i == t) ? srs[t] : 0.0f;
  #pragma unroll
  for (int i = 62; i >= 0; --i) {
    float a0 = 0.f, a1 = 0.f;
    #pragma unroll
    for (int j = i + 1; j < 64; j += 2) {
      a0 = fmaf(-sD[i * 65 + j], v[j], a0);
      if (j + 1 < 64) a1 = fmaf(-sD[i * 65 + j + 1], v[j + 1], a1);
    }
    float nv = (a0 + a1) * srs[i];
    v[i] = (i == t) ? v[i] : nv;   // nv==0 naturally for i>t (strictly-upper zeros)
  }
  #pragma unroll
  for (int i = 0; i < 64; ++i) invU[kb * 4096 + i * 64 + t] = v[i];
}

// ---------------- backward solve U * Gt = Z : 8 INDEPENDENT column-slice blocks (16 cols each).
//                  Z slice lives in LDS; diag solves are invU GEMMs; right-looking updates.
//                  All per-thread arrays statically indexed (FULL unrolls) -- no scratch spill. ----------------
__global__ __launch_bounds__(512) void k_bs(const float* __restrict__ M, const float* __restrict__ invUg,
                                            float* __restrict__ Gt) {
  __shared__ float sZ[512 * 17];     // 512 rows x 16 cols, stride 17 (bank-spread)
  __shared__ float sU[64 * 65];
  __shared__ float sI[64 * 64];
  const int t = threadIdx.x;
  const int c0 = blockIdx.x * 16;
  const int o = t & 15, q = t >> 4;  // q in [0,32): row-thread groups
  // load this block's Z slice (augmented columns of M)
  #pragma unroll
  for (int l = 0; l < 16; ++l) {
    int e = t + l * 512;
    int r = e >> 4, oo = e & 15;
    sZ[r * 17 + oo] = M[r * 640 + 512 + c0 + oo];
  }
  for (int kb = 7; kb >= 0; --kb) {
    // stage invU(kb)
    #pragma unroll
    for (int l = 0; l < 8; ++l) {
      int e = t + l * 512;
      sI[e] = invUg[kb * 4096 + e];
    }
    __syncthreads();   // covers initial sZ load (first iter) + sI staging + prior updates
    // x_kb = invU @ z_kb : read phase
    float xv[2];
    #pragma unroll
    for (int rr = 0; rr < 2; ++rr) {
      int i = q * 2 + rr;
      float a0 = 0.f, a1 = 0.f;
      #pragma unroll
      for (int k = 0; k < 64; k += 2) {
        a0 = fmaf(sI[i * 64 + k], sZ[(kb * 64 + k) * 17 + o], a0);
        a1 = fmaf(sI[i * 64 + k + 1], sZ[(kb * 64 + k + 1) * 17 + o], a1);
      }
      xv[rr] = a0 + a1;
    }
    __syncthreads();   // all reads of z_kb done before overwrite
    #pragma unroll
    for (int rr = 0; rr < 2; ++rr) {
      int i = q * 2 + rr;
      sZ[(kb * 64 + i) * 17 + o] = xv[rr];
      Gt[(kb * 64 + i) * 128 + c0 + o] = xv[rr];
    }
    __syncthreads();
    if (kb == 0) break;
    // hoist x_kb into registers once (each thread: its own column o) -- STATIC indices only
    float xk[64];
    #pragma unroll
    for (int k = 0; k < 64; ++k) xk[k] = sZ[(kb * 64 + k) * 17 + o];
    // updates: z_i -= U(i,kb) @ x_kb for i < kb
    for (int i = 0; i < kb; ++i) {
      #pragma unroll
      for (int l = 0; l < 8; ++l) {
        int e = t + l * 512;
        int r = e >> 6, k = e & 63;
        sU[r * 65 + k] = M[(i * 64 + r) * 640 + kb * 64 + k];
      }
      __syncthreads();
      #pragma unroll
      for (int rr = 0; rr < 2; ++rr) {
        int row = q * 2 + rr;
        float acc = sZ[(i * 64 + row) * 17 + o];
        #pragma unroll
        for (int k = 0; k < 64; ++k)
          acc = fmaf(-sU[row * 65 + k], xk[k], acc);
        sZ[(i * 64 + row) * 17 + o] = acc;
      }
      __syncthreads();
    }
  }
}

// ---------------- W1 = G@B1 + D21, W2 = G@B2 + D22, bias = G@Fx ----------------
__global__ void k_wass(const float* __restrict__ Gt, const float* __restrict__ H,
                       const float* __restrict__ B2, const float* __restrict__ D21,
                       const float* __restrict__ D22, const float* __restrict__ Fx,
                       float* __restrict__ W1, float* __restrict__ W2, float* __restrict__ bias) {
  int idx = blockIdx.x * 256 + threadIdx.x;
  if (idx < 16384) {
    int o = idx >> 7, j = idx & 127;
    float s = 0.f;
    for (int a = 0; a < 512; ++a) s = fmaf(Gt[a * 128 + o], H[(640 + a) * 1152 + 512 + j], s);
    W1[idx] = s + D21[idx];
  } else if (idx < 32768) {
    int q = idx - 16384;
    int o = q >> 7, j = q & 127;
    float s = 0.f;
    for (int a = 0; a < 512; ++a) s = fmaf(Gt[a * 128 + o], B2[a * 128 + j], s);
    W2[q] = s + D22[q];
  } else if (idx < 32768 + 128) {
    int o = idx - 32768;
    float s = 0.f;
    for (int a = 0; a < 512; ++a) s = fmaf(Gt[a * 128 + o], Fx[a], s);
    bias[o] = s;
  }
}

// ---------------- baseT[i][b] = xc[i] + (u @ D12^T)[b][i] ----------------
__global__ __launch_bounds__(256) void k_ud(const float* __restrict__ u, const float* __restrict__ D12,
                                            const float* __restrict__ xc, float* __restrict__ baseT) {
  __shared__ float sU[32][65];
  __shared__ float sD[32][65];
  const int t = threadIdx.x;
  const int b0 = blockIdx.x * 64, i0 = blockIdx.y * 64;
  const int tm = t & 15, tn = t >> 4;
  float acc[4][4] = {};
  for (int k0 = 0; k0 < 128; k0 += 32) {
    #pragma unroll
    for (int l = 0; l < 2; ++l) {
      int idx = t + l * 256;
      int row = idx >> 3, k4 = (idx & 7) << 2;
      float4 v = *(const float4*)&u[(b0 + row) * 128 + k0 + k4];
      sU[k4 + 0][row] = v.x; sU[k4 + 1][row] = v.y; sU[k4 + 2][row] = v.z; sU[k4 + 3][row] = v.w;
      float4 d = *(const float4*)&D12[(i0 + row) * 128 + k0 + k4];
      sD[k4 + 0][row] = d.x; sD[k4 + 1][row] = d.y; sD[k4 + 2][row] = d.z; sD[k4 + 3][row] = d.w;
    }
    __syncthreads();
    #pragma unroll
    for (int kk = 0; kk < 32; ++kk) {
      float mm[4], nn[4];
      #pragma unroll
      for (int q = 0; q < 4; ++q) mm[q] = sU[kk][tm * 4 + q];
      #pragma unroll
      for (int q = 0; q < 4; ++q) nn[q] = sD[kk][tn * 4 + q];
      #pragma unroll
      for (int c = 0; c < 4; ++c)
        #pragma unroll
        for (int r = 0; r < 4; ++r)
          acc[c][r] = fmaf(nn[c], mm[r], acc[c][r]);
    }
    __syncthreads();
  }
  #pragma unroll
  for (int c = 0; c < 4; ++c) {
    int i = i0 + tn * 4 + c;
    float xcv = xc[i];
    float4 v = make_float4(acc[c][0] + xcv, acc[c][1] + xcv, acc[c][2] + xcv, acc[c][3] + xcv);
    *(float4*)&baseT[i * BATCH + b0 + tm * 4] = v;
  }
}

// ---------------- scan: w[i] = tanh((base_i + sum_{j<i} D11[i][j] w[j]) / Lam[i]) ----------------
// Template-recursive steps: every w[] index is a COMPILE-TIME literal -> w lives in VGPRs,
// no scratch (round-7 k_scan had VGPR=72 with w[128]: partial unroll -> runtime-indexed -> spilled).
// __launch_bounds__(64,1): grid gives only 1 wave/CU anyway; allow the allocator full registers.
template<int I>
struct ScanStep {
  static __device__ __forceinline__ void run(float (&w)[128], const float* __restrict__ baseT,
                                             const float* __restrict__ D11g, const float* __restrict__ Lam,
                                             float* __restrict__ wT, int b) {
    ScanStep<I - 1>::run(w, baseT, D11g, Lam, wT, b);
    float acc0 = baseT[I * BATCH + b], acc1 = 0.f, acc2 = 0.f, acc3 = 0.f;
    const float* __restrict__ Drow = D11g + I * 128;
    #pragma unroll
    for (int j = 0; j + 4 <= I; j += 4) {
      acc0 = fmaf(w[j + 0], Drow[j + 0], acc0);
      acc1 = fmaf(w[j + 1], Drow[j + 1], acc1);
      acc2 = fmaf(w[j + 2], Drow[j + 2], acc2);
      acc3 = fmaf(w[j + 3], Drow[j + 3], acc3);
    }
    #pragma unroll
    for (int j = I & ~3; j < I; ++j) acc0 = fmaf(w[j], Drow[j], acc0);
    float zv = ((acc0 + acc1) + (acc2 + acc3)) / Lam[I];
    float az = fabsf(zv);
    float e = __expf(-2.0f * az);
    float th = (1.0f - e) / (1.0f + e);
    w[I] = copysignf(th, zv);
    wT[I * BATCH + b] = w[I];
  }
};
template<>
struct ScanStep<-1> {
  static __device__ __forceinline__ void run(float (&)[128], const float*, const float*, const float*,
                                             float*, int) {}
};

__global__ __launch_bounds__(64, 1) void k_scan(const float* __restrict__ baseT, const float* __restrict__ D11g,
                                                const float* __restrict__ Lam, float* __restrict__ wT) {
  const int b = blockIdx.x * 64 + threadIdx.x;
  float w[128];
  ScanStep<127>::run(w, baseT, D11g, Lam, wT, b);
}

// ---------------- y = w@W1^T + u@W2^T + bias ----------------
__global__ __launch_bounds__(256) void k_y(const float* __restrict__ wT, const float* __restrict__ u,
                                           const float* __restrict__ W1, const float* __restrict__ W2,
                                           const float* __restrict__ bias, float* __restrict__ y) {
  __shared__ float sA[32][65];
  __shared__ float sW[32][65];
  const int t = threadIdx.x;
  const int b0 = blockIdx.x * 64, o0 = blockIdx.y * 64;
  const int tn = t & 15, tm = t >> 4;
  float acc[4][4] = {};
  for (int k0 = 0; k0 < 128; k0 += 32) {
    #pragma unroll
    for (int l = 0; l < 2; ++l) {
      int idx = t + l * 256;
      int kk = idx >> 4, c4 = (idx & 15) << 2;
      float4 v = *(const float4*)&wT[(k0 + kk) * BATCH + b0 + c4];
      sA[kk][c4 + 0] = v.x; sA[kk][c4 + 1] = v.y; sA[kk][c4 + 2] = v.z; sA[kk][c4 + 3] = v.w;
      int row = idx >> 3, k4 = (idx & 7) << 2;
      float4 d = *(const float4*)&W1[(o0 + row) * 128 + k0 + k4];
      sW[k4 + 0][row] = d.x; sW[k4 + 1][row] = d.y; sW[k4 + 2][row] = d.z; sW[k4 + 3][row] = d.w;
    }
    __syncthreads();
    #pragma unroll
    for (int kk = 0; kk < 32; ++kk) {
      float mm[4], nn[4];
      #pragma unroll
      for (int q = 0; q < 4; ++q) mm[q] = sA[kk][tm * 4 + q];
      #pragma unroll
      for (int q = 0; q < 4; ++q) nn[q] = sW[kk][tn * 4 + q];
      #pragma unroll
      for (int r = 0; r < 4; ++r)
        #pragma unroll
        for (int c = 0; c < 4; ++c)
          acc[r][c] = fmaf(mm[r], nn[c], acc[r][c]);
    }
    __syncthreads();
  }
  for (int k0 = 0; k0 < 128; k0 += 32) {
    #pragma unroll
    for (int l = 0; l < 2; ++l) {
      int idx = t + l * 256;
      int row = idx >> 3, k4 = (idx & 7) << 2;
      float4 v = *(const float4*)&u[(b0 + row) * 128 + k0 + k4];
      sA[k4 + 0][row] = v.x; sA[k4 + 1][row] = v.y; sA[k4 + 2][row] = v.z; sA[k4 + 3][row] = v.w;
      float4 d = *(const float4*)&W2[(o0 + row) * 128 + k0 + k4];
      sW[k4 + 0][row] = d.x; sW[k4 + 1][row] = d.y; sW[k4 + 2][row] = d.z; sW[k4 + 3][row] = d.w;
    }
    __syncthreads();
    #pragma unroll
    for (int kk = 0; kk < 32; ++kk) {
      float mm[4], nn[4];
      #pragma unroll
      for (int q = 0; q < 4; ++q) mm[q] = sA[kk][tm * 4 + q];
      #pragma unroll
      for (int q = 0; q < 4; ++q) nn[q] = sW[kk][tn * 4 + q];
      #pragma unroll
      for (int r = 0; r < 4; ++r)
        #pragma unroll
        for (int c = 0; c < 4; ++c)
          acc[r][c] = fmaf(mm[r], nn[c], acc[r][c]);
    }
    __syncthreads();
  }
  #pragma unroll
  for (int r = 0; r < 4; ++r) {
    int bb = b0 + tm * 4 + r;
    float4 v = make_float4(acc[r][0] + bias[o0 + tn * 4 + 0],
                           acc[r][1] + bias[o0 + tn * 4 + 1],
                           acc[r][2] + bias[o0 + tn * 4 + 2],
                           acc[r][3] + bias[o0 + tn * 4 + 3]);
    *(float4*)&y[bb * 128 + o0 + tn * 4] = v;
  }
}

extern "C" void kernel_launch(void* const* d_in, const int* in_sizes, int n_in,
                              void* d_out, int out_size, void* d_ws, size_t ws_size,
                              hipStream_t stream) {
  const float* u   = (const float*)d_in[0];
  const float* X   = (const float*)d_in[1];
  const float* Y   = (const float*)d_in[2];
  const float* B2  = (const float*)d_in[3];
  const float* C2  = (const float*)d_in[4];
  const float* D21 = (const float*)d_in[5];
  const float* D22 = (const float*)d_in[6];
  const float* D12 = (const float*)d_in[7];
  const float* x0  = (const float*)d_in[8];

  float* ws = (float*)d_ws;
  float* H     = ws;                    // 1327104
  float* M     = H + 1327104;           // 512*640 = 327680
  float* Gt    = M + 327680;            // 65536
  float* W1    = Gt + 65536;            // 16384
  float* W2    = W1 + 16384;            // 16384
  float* D11   = W2 + 16384;            // 16384
  float* Lam   = D11 + 16384;           // 128
  float* xc    = Lam + 128;             // 128
  float* Fx    = xc + 128;              // 512
  float* bias  = Fx + 512;              // 128
  float* baseT = bias + 128 + 64;       // 128*16384 = 2097152
  float* wT    = baseT;                 // in-place
  // Dfac / invUg alias the dead H11 region (H rows 0..511 cols 0..511 are only read by
  // k_assemble, stream-ordered before the LU). 2 * 8 * 64*64 = 65536 floats = ~57 H-rows.
  float* Dfac  = H;
  float* invUg = H + 32768;
  float* y     = (float*)d_out;

  k_xtx<<<dim3(18, 18), 256, 0, stream>>>(X, H);
  k_assemble<<<388, 256, 0, stream>>>(H, Y, C2, x0, M, D11, Lam, xc, Fx);

  for (int kb = 0; kb < 8; ++kb) {
    k_lu_dp<<<16 - 2 * kb, 64, 0, stream>>>(M, Dfac, kb);
    if (kb < 7)
      k_lu_trailing<<<dim3(9 - kb, 7 - kb), 256, 0, stream>>>(M, kb);
  }

  k_inv<<<8, 64, 0, stream>>>(Dfac, invUg);
  k_bs<<<8, 512, 0, stream>>>(M, invUg, Gt);
  k_wass<<<129, 256, 0, stream>>>(Gt, H, B2, D21, D22, Fx, W1, W2, bias);

  k_ud<<<dim3(256, 2), 256, 0, stream>>>(u, D12, xc, baseT);
  k_scan<<<256, 64, 0, stream>>>(baseT, D11, Lam, wT);
  k_y<<<dim3(256, 2), 256, 0, stream>>>(wT, u, W1, W2, bias, y);
}

// Round 9
// 912.547 us; speedup vs baseline: 2.1597x; 1.0588x over previous
//
#include <hip/hip_runtime.h>
#include <math.h>

#define EPS_C 0.001f
#define BATCH 16384

// ---------------- H = X^T X + eps*I  (1152x1152), symmetric: compute bi<=bj, mirror ----------------
__global__ __launch_bounds__(256) void k_xtx(const float* __restrict__ X, float* __restrict__ H) {
  __shared__ float smem[64 * 65];
  const int bi64 = blockIdx.x, bj64 = blockIdx.y;
  if (bi64 > bj64) return;
  float (*sA)[65] = (float(*)[65])smem;
  float (*sB)[65] = (float(*)[65])(smem + 32 * 65);
  const int t = threadIdx.x;
  const int bi = bi64 * 64, bj = bj64 * 64;
  const int tj = t & 15, ti = t >> 4;
  float acc[4][4] = {};
  for (int k0 = 0; k0 < 1152; k0 += 32) {
    #pragma unroll
    for (int l = 0; l < 2; ++l) {
      int idx = t + l * 256;
      int kk = idx >> 4, c4 = (idx & 15) << 2;
      float4 va = *(const float4*)&X[(k0 + kk) * 1152 + bi + c4];
      sA[kk][c4 + 0] = va.x; sA[kk][c4 + 1] = va.y; sA[kk][c4 + 2] = va.z; sA[kk][c4 + 3] = va.w;
      float4 vb = *(const float4*)&X[(k0 + kk) * 1152 + bj + c4];
      sB[kk][c4 + 0] = vb.x; sB[kk][c4 + 1] = vb.y; sB[kk][c4 + 2] = vb.z; sB[kk][c4 + 3] = vb.w;
    }
    __syncthreads();
    #pragma unroll
    for (int kk = 0; kk < 32; ++kk) {
      float am[4], bn[4];
      #pragma unroll
      for (int q = 0; q < 4; ++q) am[q] = sA[kk][ti * 4 + q];
      #pragma unroll
      for (int q = 0; q < 4; ++q) bn[q] = sB[kk][tj * 4 + q];
      #pragma unroll
      for (int r = 0; r < 4; ++r)
        #pragma unroll
        for (int c = 0; c < 4; ++c)
          acc[r][c] = fmaf(am[r], bn[c], acc[r][c]);
    }
    __syncthreads();
  }
  #pragma unroll
  for (int r = 0; r < 4; ++r) {
    int gi = bi + ti * 4 + r;
    float vv[4];
    #pragma unroll
    for (int c = 0; c < 4; ++c) {
      vv[c] = acc[r][c];
      if (gi == bj + tj * 4 + c) vv[c] += EPS_C;
    }
    float4 o = make_float4(vv[0], vv[1], vv[2], vv[3]);
    *(float4*)&H[gi * 1152 + bj + tj * 4] = o;
  }
  if (bi64 < bj64) {
    float (*tr)[65] = (float(*)[65])smem;
    #pragma unroll
    for (int r = 0; r < 4; ++r)
      #pragma unroll
      for (int c = 0; c < 4; ++c)
        tr[tj * 4 + c][ti * 4 + r] = acc[r][c];
    __syncthreads();
    #pragma unroll
    for (int l = 0; l < 4; ++l) {
      int e = t + l * 256;
      int row = e >> 4, c4 = (e & 15) << 2;
      float4 o = make_float4(tr[row][c4], tr[row][c4 + 1], tr[row][c4 + 2], tr[row][c4 + 3]);
      *(float4*)&H[(bj + row) * 1152 + bi + c4] = o;
    }
  }
}

// ---------------- assemble M=[E^T | C2^T], D11, Lam, xc, Fx ----------------
__global__ __launch_bounds__(256) void k_assemble(const float* __restrict__ H, const float* __restrict__ Y,
                           const float* __restrict__ C2, const float* __restrict__ x0,
                           float* __restrict__ M, float* __restrict__ D11,
                           float* __restrict__ Lam, float* __restrict__ xc, float* __restrict__ Fx) {
  const int b = blockIdx.x;
  const int t = threadIdx.x;
  if (b < 256) {
    __shared__ float tA[32][33], tB[32][33], tC[32][33];
    const int R0 = (b & 15) * 32, C0 = (b >> 4) * 32;
    const int c = t & 31, rr = t >> 5;
    #pragma unroll
    for (int p = 0; p < 4; ++p) {
      int row = rr + p * 8;
      tA[row][c] = H[(C0 + row) * 1152 + R0 + c];
      tB[row][c] = H[(640 + C0 + row) * 1152 + 640 + R0 + c];
      tC[row][c] = Y[(C0 + row) * 512 + R0 + c];
    }
    __syncthreads();
    #pragma unroll
    for (int p = 0; p < 4; ++p) {
      int r = rr + p * 8;
      float val = 0.5f * (tA[c][r] + tB[c][r] + tC[c][r] - Y[(R0 + r) * 512 + C0 + c]);
      M[(R0 + r) * 640 + C0 + c] = val;
    }
  } else if (b < 320) {
    int e0 = (b - 256) * 1024;
    #pragma unroll
    for (int l = 0; l < 4; ++l) {
      int e = e0 + l * 256 + t;
      int r = e >> 7, o = e & 127;
      M[r * 640 + 512 + o] = C2[o * 512 + r];
    }
  } else if (b < 384) {
    int e = (b - 320) * 256 + t;
    int i = e >> 7, j = e & 127;
    D11[e] = (j < i) ? -H[(512 + i) * 1152 + 512 + j] : 0.0f;
  } else if (b == 384) {
    if (t < 128) Lam[t] = 0.5f * H[(512 + t) * 1152 + 512 + t];
  } else if (b == 385) {
    if (t < 128) {
      float s = 0.f;
      for (int a = 0; a < 512; ++a) s = fmaf(H[(512 + t) * 1152 + a], x0[a], s);
      xc[t] = -s;
    }
  } else {
    int r = (b - 386) * 256 + t;
    float s = 0.f;
    for (int a = 0; a < 512; ++a) s = fmaf(H[(640 + r) * 1152 + a], x0[a], s);
    Fx[r] = s;
  }
}

// ---------------- fused diag+panels: every block redundantly factors the 64x64 diag in registers
//                  (no inter-block sync); block 0 persists factored diag to Dfac (NOT in-place: race-free) ----------------
__global__ __launch_bounds__(64) void k_lu_dp(float* __restrict__ M, float* __restrict__ Dfac, int kb) {
  __shared__ float sD[64 * 65];
  __shared__ float sRD[64];
  const int t = threadIdx.x;
  const int nU = 9 - kb;
  const int pb = blockIdx.x;
  // issue panel loads early (panel strips are untouched by the diag factor)
  float v[64];
  int c = 0, rr = 0;
  if (pb < nU) {
    c = 64 * (kb + 1) + pb * 64 + t;
    #pragma unroll
    for (int i = 0; i < 64; ++i) v[i] = M[(kb * 64 + i) * 640 + c];
  } else {
    rr = 64 * (kb + 1) + (pb - nU) * 64 + t;
    #pragma unroll
    for (int i = 0; i < 16; ++i) *(float4*)&v[i * 4] = *(const float4*)&M[rr * 640 + kb * 64 + i * 4];
  }
  // redundant in-register LU factor of diag (reads ORIGINAL M diag; M's diag is never overwritten)
  {
    const float* blk = M + kb * 64 * 640 + kb * 64;
    float col[64];
    #pragma unroll
    for (int r = 0; r < 64; ++r) col[r] = blk[r * 640 + t];
    float invp = 1.0f;
    #pragma unroll
    for (int k = 0; k < 64; ++k) {
      float piv = __shfl(col[k], k);
      float inv = 1.0f / piv;
      if (t == k) invp = inv;
      float m = col[k] * inv;
      bool act = t > k;
      #pragma unroll
      for (int r = k + 1; r < 64; ++r) {
        float ckr = __shfl(col[r], k);
        if (act) col[r] -= ckr * m;
      }
    }
    #pragma unroll
    for (int r = 0; r < 64; ++r) {
      if (r > t) col[r] *= invp;
      sD[r * 65 + t] = col[r];
      if (pb == 0) Dfac[kb * 4096 + r * 64 + t] = col[r];
    }
    sRD[t] = invp;  // == 1/sD[t*65+t] bitwise
  }
  __syncthreads();
  if (pb < nU) {
    #pragma unroll
    for (int i = 1; i < 64; ++i) {
      float a0 = v[i], a1 = 0.f;
      #pragma unroll
      for (int j = 0; j < i; j += 2) {
        a0 = fmaf(-sD[i * 65 + j], v[j], a0);
        if (j + 1 < i) a1 = fmaf(-sD[i * 65 + j + 1], v[j + 1], a1);
      }
      v[i] = a0 + a1;
    }
    #pragma unroll
    for (int i = 0; i < 64; ++i) M[(kb * 64 + i) * 640 + c] = v[i];
  } else {
    #pragma unroll
    for (int j = 0; j < 64; ++j) {
      float a0 = v[j], a1 = 0.f;
      #pragma unroll
      for (int i = 0; i < j; i += 2) {
        a0 = fmaf(-v[i], sD[i * 65 + j], a0);
        if (i + 1 < j) a1 = fmaf(-v[i + 1], sD[(i + 1) * 65 + j], a1);
      }
      v[j] = (a0 + a1) * sRD[j];
    }
    #pragma unroll
    for (int i = 0; i < 16; ++i) *(float4*)&M[rr * 640 + kb * 64 + i * 4] = *(float4*)&v[i * 4];
  }
}

// ---------------- trailing update: A22 -= L21 * U12 (cols include augmented) ----------------
__global__ __launch_bounds__(256) void k_lu_trailing(float* __restrict__ M, int kb) {
  __shared__ float sL[32][65];
  __shared__ float sU[32][65];
  const int t = threadIdx.x;
  const int base = 64 * (kb + 1);
  const int r0 = base + blockIdx.y * 64, c0 = base + blockIdx.x * 64;
  const int tj = t & 15, ti = t >> 4;
  float acc[4][4] = {};
  for (int k0 = 0; k0 < 64; k0 += 32) {
    #pragma unroll
    for (int l = 0; l < 2; ++l) {
      int idx = t + l * 256;
      int row = idx >> 3, k4 = (idx & 7) << 2;
      float4 v = *(const float4*)&M[(r0 + row) * 640 + kb * 64 + k0 + k4];
      sL[k4 + 0][row] = v.x; sL[k4 + 1][row] = v.y; sL[k4 + 2][row] = v.z; sL[k4 + 3][row] = v.w;
      int kk = idx >> 4, c4 = (idx & 15) << 2;
      float4 u4 = *(const float4*)&M[(kb * 64 + k0 + kk) * 640 + c0 + c4];
      sU[kk][c4 + 0] = u4.x; sU[kk][c4 + 1] = u4.y; sU[kk][c4 + 2] = u4.z; sU[kk][c4 + 3] = u4.w;
    }
    __syncthreads();
    #pragma unroll
    for (int kk = 0; kk < 32; ++kk) {
      float am[4], bn[4];
      #pragma unroll
      for (int q = 0; q < 4; ++q) am[q] = sL[kk][ti * 4 + q];
      #pragma unroll
      for (int q = 0; q < 4; ++q) bn[q] = sU[kk][tj * 4 + q];
      #pragma unroll
      for (int r = 0; r < 4; ++r)
        #pragma unroll
        for (int c = 0; c < 4; ++c)
          acc[r][c] = fmaf(am[r], bn[c], acc[r][c]);
    }
    __syncthreads();
  }
  #pragma unroll
  for (int r = 0; r < 4; ++r) {
    float4 old = *(float4*)&M[(r0 + ti * 4 + r) * 640 + c0 + tj * 4];
    old.x -= acc[r][0]; old.y -= acc[r][1]; old.z -= acc[r][2]; old.w -= acc[r][3];
    *(float4*)&M[(r0 + ti * 4 + r) * 640 + c0 + tj * 4] = old;
  }
}

// ---------------- invert each factored 64x64 diag block: invU[kb] = U_kk^-1 (8 parallel blocks) ----------------
__global__ __launch_bounds__(64) void k_inv(const float* __restrict__ Dfac, float* __restrict__ invU) {
  __shared__ float sD[64 * 65];
  __shared__ float srs[64];
  const int t = threadIdx.x;
  const int kb = blockIdx.x;
  for (int l = 0; l < 64; ++l) sD[l * 65 + t] = Dfac[kb * 4096 + l * 64 + t];
  __syncthreads();
  srs[t] = 1.0f / sD[t * 65 + t];
  __syncthreads();
  // column t of U^-1 via back-substitution, fully unrolled, registers only
  float v[64];
  #pragma unroll
  for (int i = 0; i < 64; ++i) v[i] = (i == t) ? srs[t] : 0.0f;
  #pragma unroll
  for (int i = 62; i >= 0; --i) {
    float a0 = 0.f, a1 = 0.f;
    #pragma unroll
    for (int j = i + 1; j < 64; j += 2) {
      a0 = fmaf(-sD[i * 65 + j], v[j], a0);
      if (j + 1 < 64) a1 = fmaf(-sD[i * 65 + j + 1], v[j + 1], a1);
    }
    float nv = (a0 + a1) * srs[i];
    v[i] = (i == t) ? v[i] : nv;   // nv==0 naturally for i>t (strictly-upper zeros)
  }
  #pragma unroll
  for (int i = 0; i < 64; ++i) invU[kb * 4096 + i * 64 + t] = v[i];
}

// ---------------- backward solve U * Gt = Z : 8 INDEPENDENT column-slice blocks (16 cols each).
//                  launch_bounds(512,2): grid is 8 blocks -> 2 waves/SIMD is the max achievable
//                  occupancy; give the allocator the full 256-VGPR budget so xk[] stays in regs
//                  and staging pipelines. sI padded to stride 65 (stride-64 was a 4-way conflict
//                  on every solve read). U tiles double-buffered through registers (bufA/bufB). ----------------
__global__ __launch_bounds__(512, 2) void k_bs(const float* __restrict__ M, const float* __restrict__ invUg,
                                               float* __restrict__ Gt) {
  __shared__ float sZ[512 * 17];     // 512 rows x 16 cols, stride 17 (bank-spread)
  __shared__ float sU[64 * 65];
  __shared__ float sI[64 * 65];      // padded: (i*65+k)%32 varies with i
  const int t = threadIdx.x;
  const int c0 = blockIdx.x * 16;
  const int o = t & 15, q = t >> 4;  // q in [0,32): row-thread groups
  // load this block's Z slice (augmented columns of M)
  #pragma unroll
  for (int l = 0; l < 16; ++l) {
    int e = t + l * 512;
    int r = e >> 4, oo = e & 15;
    sZ[r * 17 + oo] = M[r * 640 + 512 + c0 + oo];
  }
  for (int kb = 7; kb >= 0; --kb) {
    // stage invU(kb), padded stride
    #pragma unroll
    for (int l = 0; l < 8; ++l) {
      int e = t + l * 512;
      int r = e >> 6, k = e & 63;
      sI[r * 65 + k] = invUg[kb * 4096 + r * 64 + k];
    }
    __syncthreads();   // covers initial sZ load (first iter) + sI staging + prior updates
    // x_kb = invU @ z_kb : read phase
    float xv[2];
    #pragma unroll
    for (int rr = 0; rr < 2; ++rr) {
      int i = q * 2 + rr;
      float a0 = 0.f, a1 = 0.f;
      #pragma unroll
      for (int k = 0; k < 64; k += 2) {
        a0 = fmaf(sI[i * 65 + k], sZ[(kb * 64 + k) * 17 + o], a0);
        a1 = fmaf(sI[i * 65 + k + 1], sZ[(kb * 64 + k + 1) * 17 + o], a1);
      }
      xv[rr] = a0 + a1;
    }
    __syncthreads();   // all reads of z_kb done before overwrite
    #pragma unroll
    for (int rr = 0; rr < 2; ++rr) {
      int i = q * 2 + rr;
      sZ[(kb * 64 + i) * 17 + o] = xv[rr];
      Gt[(kb * 64 + i) * 128 + c0 + o] = xv[rr];
    }
    __syncthreads();
    if (kb == 0) break;
    // hoist x_kb into registers once (each thread: its own column o) -- STATIC indices only
    float xk[64];
    #pragma unroll
    for (int k = 0; k < 64; ++k) xk[k] = sZ[(kb * 64 + k) * 17 + o];
    // updates: z_i -= U(i,kb) @ x_kb for i < kb, with reg-staged double-buffered U tiles
    float bufA[8], bufB[8];
    #pragma unroll
    for (int l = 0; l < 8; ++l) {
      int e = t + l * 512;
      int r = e >> 6, k = e & 63;
      bufA[l] = M[r * 640 + kb * 64 + k];          // i = 0 tile
    }
    for (int i = 0; i < kb; ++i) {
      #pragma unroll
      for (int l = 0; l < 8; ++l) {
        int e = t + l * 512;
        int r = e >> 6, k = e & 63;
        sU[r * 65 + k] = bufA[l];
      }
      if (i + 1 < kb) {
        #pragma unroll
        for (int l = 0; l < 8; ++l) {
          int e = t + l * 512;
          int r = e >> 6, k = e & 63;
          bufB[l] = M[((i + 1) * 64 + r) * 640 + kb * 64 + k];   // prefetch next tile
        }
      }
      __syncthreads();
      #pragma unroll
      for (int rr = 0; rr < 2; ++rr) {
        int row = q * 2 + rr;
        float acc = sZ[(i * 64 + row) * 17 + o];
        #pragma unroll
        for (int k = 0; k < 64; ++k)
          acc = fmaf(-sU[row * 65 + k], xk[k], acc);
        sZ[(i * 64 + row) * 17 + o] = acc;
      }
      #pragma unroll
      for (int l = 0; l < 8; ++l) bufA[l] = bufB[l];
      __syncthreads();   // compute done reading sU before next iteration overwrites it
    }
  }
}

// ---------------- W1 = G@B1 + D21, W2 = G@B2 + D22, bias = G@Fx ----------------
__global__ void k_wass(const float* __restrict__ Gt, const float* __restrict__ H,
                       const float* __restrict__ B2, const float* __restrict__ D21,
                       const float* __restrict__ D22, const float* __restrict__ Fx,
                       float* __restrict__ W1, float* __restrict__ W2, float* __restrict__ bias) {
  int idx = blockIdx.x * 256 + threadIdx.x;
  if (idx < 16384) {
    int o = idx >> 7, j = idx & 127;
    float s = 0.f;
    for (int a = 0; a < 512; ++a) s = fmaf(Gt[a * 128 + o], H[(640 + a) * 1152 + 512 + j], s);
    W1[idx] = s + D21[idx];
  } else if (idx < 32768) {
    int q = idx - 16384;
    int o = q >> 7, j = q & 127;
    float s = 0.f;
    for (int a = 0; a < 512; ++a) s = fmaf(Gt[a * 128 + o], B2[a * 128 + j], s);
    W2[q] = s + D22[q];
  } else if (idx < 32768 + 128) {
    int o = idx - 32768;
    float s = 0.f;
    for (int a = 0; a < 512; ++a) s = fmaf(Gt[a * 128 + o], Fx[a], s);
    bias[o] = s;
  }
}

// ---------------- baseT[i][b] = xc[i] + (u @ D12^T)[b][i] ----------------
__global__ __launch_bounds__(256) void k_ud(const float* __restrict__ u, const float* __restrict__ D12,
                                            const float* __restrict__ xc, float* __restrict__ baseT) {
  __shared__ float sU[32][65];
  __shared__ float sD[32][65];
  const int t = threadIdx.x;
  const int b0 = blockIdx.x * 64, i0 = blockIdx.y * 64;
  const int tm = t & 15, tn = t >> 4;
  float acc[4][4] = {};
  for (int k0 = 0; k0 < 128; k0 += 32) {
    #pragma unroll
    for (int l = 0; l < 2; ++l) {
      int idx = t + l * 256;
      int row = idx >> 3, k4 = (idx & 7) << 2;
      float4 v = *(const float4*)&u[(b0 + row) * 128 + k0 + k4];
      sU[k4 + 0][row] = v.x; sU[k4 + 1][row] = v.y; sU[k4 + 2][row] = v.z; sU[k4 + 3][row] = v.w;
      float4 d = *(const float4*)&D12[(i0 + row) * 128 + k0 + k4];
      sD[k4 + 0][row] = d.x; sD[k4 + 1][row] = d.y; sD[k4 + 2][row] = d.z; sD[k4 + 3][row] = d.w;
    }
    __syncthreads();
    #pragma unroll
    for (int kk = 0; kk < 32; ++kk) {
      float mm[4], nn[4];
      #pragma unroll
      for (int q = 0; q < 4; ++q) mm[q] = sU[kk][tm * 4 + q];
      #pragma unroll
      for (int q = 0; q < 4; ++q) nn[q] = sD[kk][tn * 4 + q];
      #pragma unroll
      for (int c = 0; c < 4; ++c)
        #pragma unroll
        for (int r = 0; r < 4; ++r)
          acc[c][r] = fmaf(nn[c], mm[r], acc[c][r]);
    }
    __syncthreads();
  }
  #pragma unroll
  for (int c = 0; c < 4; ++c) {
    int i = i0 + tn * 4 + c;
    float xcv = xc[i];
    float4 v = make_float4(acc[c][0] + xcv, acc[c][1] + xcv, acc[c][2] + xcv, acc[c][3] + xcv);
    *(float4*)&baseT[i * BATCH + b0 + tm * 4] = v;
  }
}

// ---------------- scan: w[i] = tanh((base_i + sum_{j<i} D11[i][j] w[j]) / Lam[i]) ----------------
// Template-recursive steps: every w[] index is a COMPILE-TIME literal -> w lives in VGPRs.
template<int I>
struct ScanStep {
  static __device__ __forceinline__ void run(float (&w)[128], const float* __restrict__ baseT,
                                             const float* __restrict__ D11g, const float* __restrict__ Lam,
                                             float* __restrict__ wT, int b) {
    ScanStep<I - 1>::run(w, baseT, D11g, Lam, wT, b);
    float acc0 = baseT[I * BATCH + b], acc1 = 0.f, acc2 = 0.f, acc3 = 0.f;
    const float* __restrict__ Drow = D11g + I * 128;
    #pragma unroll
    for (int j = 0; j + 4 <= I; j += 4) {
      acc0 = fmaf(w[j + 0], Drow[j + 0], acc0);
      acc1 = fmaf(w[j + 1], Drow[j + 1], acc1);
      acc2 = fmaf(w[j + 2], Drow[j + 2], acc2);
      acc3 = fmaf(w[j + 3], Drow[j + 3], acc3);
    }
    #pragma unroll
    for (int j = I & ~3; j < I; ++j) acc0 = fmaf(w[j], Drow[j], acc0);
    float zv = ((acc0 + acc1) + (acc2 + acc3)) / Lam[I];
    float az = fabsf(zv);
    float e = __expf(-2.0f * az);
    float th = (1.0f - e) / (1.0f + e);
    w[I] = copysignf(th, zv);
    wT[I * BATCH + b] = w[I];
  }
};
template<>
struct ScanStep<-1> {
  static __device__ __forceinline__ void run(float (&)[128], const float*, const float*, const float*,
                                             float*, int) {}
};

__global__ __launch_bounds__(64, 1) void k_scan(const float* __restrict__ baseT, const float* __restrict__ D11g,
                                                const float* __restrict__ Lam, float* __restrict__ wT) {
  const int b = blockIdx.x * 64 + threadIdx.x;
  float w[128];
  ScanStep<127>::run(w, baseT, D11g, Lam, wT, b);
}

// ---------------- y = w@W1^T + u@W2^T + bias ----------------
__global__ __launch_bounds__(256) void k_y(const float* __restrict__ wT, const float* __restrict__ u,
                                           const float* __restrict__ W1, const float* __restrict__ W2,
                                           const float* __restrict__ bias, float* __restrict__ y) {
  __shared__ float sA[32][65];
  __shared__ float sW[32][65];
  const int t = threadIdx.x;
  const int b0 = blockIdx.x * 64, o0 = blockIdx.y * 64;
  const int tn = t & 15, tm = t >> 4;
  float acc[4][4] = {};
  for (int k0 = 0; k0 < 128; k0 += 32) {
    #pragma unroll
    for (int l = 0; l < 2; ++l) {
      int idx = t + l * 256;
      int kk = idx >> 4, c4 = (idx & 15) << 2;
      float4 v = *(const float4*)&wT[(k0 + kk) * BATCH + b0 + c4];
      sA[kk][c4 + 0] = v.x; sA[kk][c4 + 1] = v.y; sA[kk][c4 + 2] = v.z; sA[kk][c4 + 3] = v.w;
      int row = idx >> 3, k4 = (idx & 7) << 2;
      float4 d = *(const float4*)&W1[(o0 + row) * 128 + k0 + k4];
      sW[k4 + 0][row] = d.x; sW[k4 + 1][row] = d.y; sW[k4 + 2][row] = d.z; sW[k4 + 3][row] = d.w;
    }
    __syncthreads();
    #pragma unroll
    for (int kk = 0; kk < 32; ++kk) {
      float mm[4], nn[4];
      #pragma unroll
      for (int q = 0; q < 4; ++q) mm[q] = sA[kk][tm * 4 + q];
      #pragma unroll
      for (int q = 0; q < 4; ++q) nn[q] = sW[kk][tn * 4 + q];
      #pragma unroll
      for (int r = 0; r < 4; ++r)
        #pragma unroll
        for (int c = 0; c < 4; ++c)
          acc[r][c] = fmaf(mm[r], nn[c], acc[r][c]);
    }
    __syncthreads();
  }
  for (int k0 = 0; k0 < 128; k0 += 32) {
    #pragma unroll
    for (int l = 0; l < 2; ++l) {
      int idx = t + l * 256;
      int row = idx >> 3, k4 = (idx & 7) << 2;
      float4 v = *(const float4*)&u[(b0 + row) * 128 + k0 + k4];
      sA[k4 + 0][row] = v.x; sA[k4 + 1][row] = v.y; sA[k4 + 2][row] = v.z; sA[k4 + 3][row] = v.w;
      float4 d = *(const float4*)&W2[(o0 + row) * 128 + k0 + k4];
      sW[k4 + 0][row] = d.x; sW[k4 + 1][row] = d.y; sW[k4 + 2][row] = d.z; sW[k4 + 3][row] = d.w;
    }
    __syncthreads();
    #pragma unroll
    for (int kk = 0; kk < 32; ++kk) {
      float mm[4], nn[4];
      #pragma unroll
      for (int q = 0; q < 4; ++q) mm[q] = sA[kk][tm * 4 + q];
      #pragma unroll
      for (int q = 0; q < 4; ++q) nn[q] = sW[kk][tn * 4 + q];
      #pragma unroll
      for (int r = 0; r < 4; ++r)
        #pragma unroll
        for (int c = 0; c < 4; ++c)
          acc[r][c] = fmaf(mm[r], nn[c], acc[r][c]);
    }
    __syncthreads();
  }
  #pragma unroll
  for (int r = 0; r < 4; ++r) {
    int bb = b0 + tm * 4 + r;
    float4 v = make_float4(acc[r][0] + bias[o0 + tn * 4 + 0],
                           acc[r][1] + bias[o0 + tn * 4 + 1],
                           acc[r][2] + bias[o0 + tn * 4 + 2],
                           acc[r][3] + bias[o0 + tn * 4 + 3]);
    *(float4*)&y[bb * 128 + o0 + tn * 4] = v;
  }
}

extern "C" void kernel_launch(void* const* d_in, const int* in_sizes, int n_in,
                              void* d_out, int out_size, void* d_ws, size_t ws_size,
                              hipStream_t stream) {
  const float* u   = (const float*)d_in[0];
  const float* X   = (const float*)d_in[1];
  const float* Y   = (const float*)d_in[2];
  const float* B2  = (const float*)d_in[3];
  const float* C2  = (const float*)d_in[4];
  const float* D21 = (const float*)d_in[5];
  const float* D22 = (const float*)d_in[6];
  const float* D12 = (const float*)d_in[7];
  const float* x0  = (const float*)d_in[8];

  float* ws = (float*)d_ws;
  float* H     = ws;                    // 1327104
  float* M     = H + 1327104;           // 512*640 = 327680
  float* Gt    = M + 327680;            // 65536
  float* W1    = Gt + 65536;            // 16384
  float* W2    = W1 + 16384;            // 16384
  float* D11   = W2 + 16384;            // 16384
  float* Lam   = D11 + 16384;           // 128
  float* xc    = Lam + 128;             // 128
  float* Fx    = xc + 128;              // 512
  float* bias  = Fx + 512;              // 128
  float* baseT = bias + 128 + 64;       // 128*16384 = 2097152
  float* wT    = baseT;                 // in-place
  // Dfac / invUg alias the dead H11 region (H rows 0..511 cols 0..511 are only read by
  // k_assemble, stream-ordered before the LU). 2 * 8 * 64*64 = 65536 floats = ~57 H-rows.
  float* Dfac  = H;
  float* invUg = H + 32768;
  float* y     = (float*)d_out;

  k_xtx<<<dim3(18, 18), 256, 0, stream>>>(X, H);
  k_assemble<<<388, 256, 0, stream>>>(H, Y, C2, x0, M, D11, Lam, xc, Fx);

  for (int kb = 0; kb < 8; ++kb) {
    k_lu_dp<<<16 - 2 * kb, 64, 0, stream>>>(M, Dfac, kb);
    if (kb < 7)
      k_lu_trailing<<<dim3(9 - kb, 7 - kb), 256, 0, stream>>>(M, kb);
  }

  k_inv<<<8, 64, 0, stream>>>(Dfac, invUg);
  k_bs<<<8, 512, 0, stream>>>(M, invUg, Gt);
  k_wass<<<129, 256, 0, stream>>>(Gt, H, B2, D21, D22, Fx, W1, W2, bias);

  k_ud<<<dim3(256, 2), 256, 0, stream>>>(u, D12, xc, baseT);
  k_scan<<<256, 64, 0, stream>>>(baseT, D11, Lam, wT);
  k_y<<<dim3(256, 2), 256, 0, stream>>>(wT, u, W1, W2, bias, y);
}